// Round 1
// baseline (5312.298 us; speedup 1.0000x reference)
//
#include <hip/hip_runtime.h>
#include <math.h>

constexpr int B   = 128;
constexpr int S   = 64;
constexpr int D0  = 768;
constexpr int H   = 256;
constexpr int KW  = 7;
constexpr int NC  = 3;
constexpr int T70 = S + KW - 1;  // 70
constexpr float EPSF = 1e-12f;

// ---------- conv weight transpose: cw[d,7,2,H] -> wT[(k*2+c)*d+dd][H] ----------
__global__ __launch_bounds__(256) void k_transpose_w(const float* __restrict__ cw,
                                                     float* __restrict__ wT, int d) {
  int idx = blockIdx.x * 256 + threadIdx.x;
  int total = d * KW * 2 * H;
  if (idx >= total) return;
  int h = idx & (H - 1);
  int rest = idx >> 8;          // (dd*7 + k)*2 + c
  int c = rest & 1;
  int kdd = rest >> 1;
  int k = kdd % KW;
  int dd = kdd / KW;
  wT[((size_t)((k * 2 + c) * d) + dd) * H + h] = cw[idx];
}

// ---------- mean over axis 1 of [B,T,F] -> [B,F] ----------
__global__ __launch_bounds__(256) void k_mean_rows(const float* __restrict__ x,
                                                   float* __restrict__ out,
                                                   int T, int F, float inv) {
  int idx = blockIdx.x * 256 + threadIdx.x;
  if (idx >= B * F) return;
  int b = idx / F, f = idx % F;
  const float* p = x + (size_t)b * T * F + f;
  float s = 0.f;
  for (int t = 0; t < T; ++t) s += p[(size_t)t * F];
  out[idx] = s * inv;
}

// ---------- attention matrix 1/(1+sqrt(max(|xi|^2+|xj|^2-2xi.xj,0)+eps)) ----------
// X1,X2: [B,W,D] row-major. STORE: write att[B,W,W]; SUMS: write row sums la, col sums ra.
template<int W, int D, bool STORE, bool SUMS>
__global__ __launch_bounds__(256) void k_att(const float* __restrict__ X1,
                                             const float* __restrict__ X2,
                                             float* __restrict__ att,
                                             float* __restrict__ la,
                                             float* __restrict__ ra) {
  constexpr int Wp = (W <= 64) ? 64 : 80;
  constexpr int TI = Wp / 16;
  constexpr int KT = 32;
  __shared__ float As[KT][Wp + 1];
  __shared__ float Bs[KT][Wp + 1];
  __shared__ float n1s[Wp];
  __shared__ float n2s[Wp];
  __shared__ float att_s[SUMS ? (W * W) : 1];

  const int b = blockIdx.x;
  const int tid = threadIdx.x;
  const float* __restrict__ x1 = X1 + (size_t)b * W * D;
  const float* __restrict__ x2 = X2 + (size_t)b * W * D;

  const int ty = tid >> 4, tx = tid & 15;
  const int i0 = ty * TI, j0 = tx * TI;

  float acc[TI][TI];
#pragma unroll
  for (int ii = 0; ii < TI; ++ii)
#pragma unroll
    for (int jj = 0; jj < TI; ++jj) acc[ii][jj] = 0.f;
  float na1 = 0.f, na2 = 0.f;

  for (int kk0 = 0; kk0 < D; kk0 += KT) {
    __syncthreads();
    for (int idx = tid; idx < Wp * KT; idx += 256) {
      const int i = idx >> 5, kk = idx & 31;
      float v1 = 0.f, v2 = 0.f;
      if (i < W) {
        v1 = x1[(size_t)i * D + kk0 + kk];
        v2 = x2[(size_t)i * D + kk0 + kk];
      }
      As[kk][i] = v1;
      Bs[kk][i] = v2;
    }
    __syncthreads();
#pragma unroll
    for (int kk = 0; kk < KT; ++kk) {
      float a[TI], bb[TI];
#pragma unroll
      for (int ii = 0; ii < TI; ++ii) a[ii] = As[kk][i0 + ii];
#pragma unroll
      for (int jj = 0; jj < TI; ++jj) bb[jj] = Bs[kk][j0 + jj];
#pragma unroll
      for (int ii = 0; ii < TI; ++ii)
#pragma unroll
        for (int jj = 0; jj < TI; ++jj)
          acc[ii][jj] = fmaf(a[ii], bb[jj], acc[ii][jj]);
    }
    if (tid < W) {
#pragma unroll
      for (int kk = 0; kk < KT; ++kk) { float v = As[kk][tid]; na1 = fmaf(v, v, na1); }
    }
    if (tid >= 128 && tid < 128 + W) {
#pragma unroll
      for (int kk = 0; kk < KT; ++kk) { float v = Bs[kk][tid - 128]; na2 = fmaf(v, v, na2); }
    }
  }
  if (tid < W) n1s[tid] = na1;
  if (tid >= 128 && tid < 128 + W) n2s[tid - 128] = na2;
  __syncthreads();

#pragma unroll
  for (int ii = 0; ii < TI; ++ii) {
    const int i = i0 + ii;
#pragma unroll
    for (int jj = 0; jj < TI; ++jj) {
      const int j = j0 + jj;
      if (i < W && j < W) {
        float sq = n1s[i] + n2s[j] - 2.f * acc[ii][jj];
        sq = fmaxf(sq, 0.f);
        const float v = 1.f / (1.f + sqrtf(sq + EPSF));
        if (STORE) att[((size_t)b * W + i) * W + j] = v;
        if (SUMS)  att_s[i * W + j] = v;
      }
    }
  }
  if (SUMS) {
    __syncthreads();
    if (tid < W) {
      float sum = 0.f;
      for (int j = 0; j < W; ++j) sum += att_s[tid * W + j];
      la[b * W + tid] = sum;
    }
    if (tid >= 128 && tid < 128 + W) {
      const int j = tid - 128;
      float sum = 0.f;
      for (int i = 0; i < W; ++i) sum += att_s[i * W + j];
      ra[b * W + j] = sum;
    }
  }
}

// ---------- x1a[b,i,d] = sum_j att[b,i,j]*aW[j,d]; x2a[b,i,d] = sum_j att[b,j,i]*aW[j,d] ----------
template<int D>
__global__ __launch_bounds__(256) void k_xa(const float* __restrict__ att,
                                            const float* __restrict__ aW,
                                            float* __restrict__ x1a,
                                            float* __restrict__ x2a) {
  __shared__ float a_s[S][S];
  const int b = blockIdx.x;
  const int tid = threadIdx.x;
  for (int idx = tid; idx < S * S; idx += 256)
    a_s[idx >> 6][idx & 63] = att[(size_t)b * S * S + idx];
  __syncthreads();
  for (int i0 = 0; i0 < S; i0 += 8) {
    for (int d0 = 0; d0 < D; d0 += 256) {
      const int d = d0 + tid;
      float acc1[8] = {0.f,0.f,0.f,0.f,0.f,0.f,0.f,0.f};
      float acc2[8] = {0.f,0.f,0.f,0.f,0.f,0.f,0.f,0.f};
      for (int j = 0; j < S; ++j) {
        const float w = aW[(size_t)j * D + d];
#pragma unroll
        for (int ii = 0; ii < 8; ++ii) {
          acc1[ii] = fmaf(a_s[i0 + ii][j], w, acc1[ii]);
          acc2[ii] = fmaf(a_s[j][i0 + ii], w, acc2[ii]);
        }
      }
#pragma unroll
      for (int ii = 0; ii < 8; ++ii) {
        x1a[((size_t)b * S + i0 + ii) * D + d] = acc1[ii];
        x2a[((size_t)b * S + i0 + ii) * D + d] = acc2[ii];
      }
    }
  }
}

// ---------- conv as im2col GEMM, fused bias+tanh ----------
// outT[b,t,h] = tanh(cb[h] + sum_{k,c,dd} src_c[b, t+k-6, dd] * wT[(k*2+c)*DPC+dd][h])
template<int DPC>
__global__ __launch_bounds__(256) void k_conv(const float* __restrict__ X,
                                              const float* __restrict__ XA,
                                              const float* __restrict__ wT,
                                              const float* __restrict__ bias,
                                              float* __restrict__ outT) {
  constexpr int CHUNKS_D = DPC / 32;
  __shared__ float As[32][68];   // [kk][row], pad 68: conflict-free-ish, 16B-aligned rows
  __shared__ float Bs[32][64];
  const int tid = threadIdx.x;
  const int n0 = blockIdx.x * 64;
  const int m0 = blockIdx.y * 64;

  const int a_kk = tid & 31;
  const int a_r = tid >> 5;  // 0..7

  size_t boff[8];
  int tv[8];
#pragma unroll
  for (int rr = 0; rr < 8; ++rr) {
    int m = m0 + a_r + rr * 8;
    int bb = m / T70, t = m % T70;
    boff[rr] = (size_t)bb * S * DPC;
    tv[rr] = t - (KW - 1);
  }

  float acc[4][4] = {};
  const int ty = tid >> 4, tx = tid & 15;
  const int r0 = ty * 4, c0 = tx * 4;

  for (int kc = 0; kc < 2 * KW; ++kc) {
    const int k = kc >> 1;
    const float* __restrict__ src = (kc & 1) ? XA : X;
    for (int dq = 0; dq < CHUNKS_D; ++dq) {
      const int dd0 = dq * 32;
      const int kk0 = kc * DPC + dd0;
      __syncthreads();
#pragma unroll
      for (int rr = 0; rr < 8; ++rr) {
        const int s = tv[rr] + k;
        float v = 0.f;
        if (s >= 0 && s < S) v = src[boff[rr] + (size_t)s * DPC + dd0 + a_kk];
        As[a_kk][a_r + rr * 8] = v;
      }
#pragma unroll
      for (int rr = 0; rr < 8; ++rr) {
        const int idx = tid + rr * 256;
        const int kk = idx >> 6, col = idx & 63;
        Bs[kk][col] = wT[(size_t)(kk0 + kk) * H + n0 + col];
      }
      __syncthreads();
#pragma unroll
      for (int kk = 0; kk < 32; ++kk) {
        const float4 av = *reinterpret_cast<const float4*>(&As[kk][r0]);
        const float4 bv = *reinterpret_cast<const float4*>(&Bs[kk][c0]);
        const float a4[4] = {av.x, av.y, av.z, av.w};
        const float b4[4] = {bv.x, bv.y, bv.z, bv.w};
#pragma unroll
        for (int ii = 0; ii < 4; ++ii)
#pragma unroll
          for (int jj = 0; jj < 4; ++jj)
            acc[ii][jj] = fmaf(a4[ii], b4[jj], acc[ii][jj]);
      }
    }
  }
#pragma unroll
  for (int ii = 0; ii < 4; ++ii) {
    const int m = m0 + r0 + ii;
    float4 o;
    o.x = tanhf(acc[ii][0] + bias[n0 + c0 + 0]);
    o.y = tanhf(acc[ii][1] + bias[n0 + c0 + 1]);
    o.z = tanhf(acc[ii][2] + bias[n0 + c0 + 2]);
    o.w = tanhf(acc[ii][3] + bias[n0 + c0 + 3]);
    *reinterpret_cast<float4*>(&outT[(size_t)m * H + n0 + c0]) = o;
  }
}

// ---------- attention-weighted window pool: out[b,s,h] = sum_{j<7} xc[b,s+j,h]*a[b,s+j] ----------
__global__ __launch_bounds__(256) void k_wpool(const float* __restrict__ xc,
                                               const float* __restrict__ a,
                                               float* __restrict__ out) {
  int idx = blockIdx.x * 256 + threadIdx.x;
  if (idx >= B * S * H) return;
  int h = idx & (H - 1);
  int rest = idx >> 8;
  int s = rest & (S - 1), b = rest >> 6;
  const float* xp = xc + ((size_t)b * T70 + s) * H + h;
  const float* ap = a + b * T70 + s;
  float acc = 0.f;
#pragma unroll
  for (int j = 0; j < KW; ++j) acc = fmaf(xp[(size_t)j * H], ap[j], acc);
  out[idx] = acc;
}

// ---------- cosine sims + final tiny GEMM ----------
__global__ __launch_bounds__(256) void k_final(const float* __restrict__ LO0,
                                               const float* __restrict__ RO0,
                                               const float* __restrict__ LO1,
                                               const float* __restrict__ RO1,
                                               const float* __restrict__ LO2,
                                               const float* __restrict__ RO2,
                                               const float* __restrict__ out_w,
                                               const float* __restrict__ out_b,
                                               float* __restrict__ out) {
  const int b = blockIdx.x;
  const int tid = threadIdx.x;
  __shared__ float red[3][4];
  __shared__ float sims[3];
  const float* Ls[3] = {LO0 + (size_t)b * D0, LO1 + (size_t)b * H, LO2 + (size_t)b * H};
  const float* Rs[3] = {RO0 + (size_t)b * D0, RO1 + (size_t)b * H, RO2 + (size_t)b * H};
  const int dims[3] = {D0, H, H};
#pragma unroll
  for (int p = 0; p < 3; ++p) {
    float dot = 0.f, q1 = 0.f, q2 = 0.f;
    for (int i = tid; i < dims[p]; i += 256) {
      const float v1 = Ls[p][i], v2 = Rs[p][i];
      dot = fmaf(v1, v2, dot);
      q1  = fmaf(v1, v1, q1);
      q2  = fmaf(v2, v2, q2);
    }
#pragma unroll
    for (int off = 32; off > 0; off >>= 1) {
      dot += __shfl_down(dot, off);
      q1  += __shfl_down(q1, off);
      q2  += __shfl_down(q2, off);
    }
    if ((tid & 63) == 0) { red[0][tid >> 6] = dot; red[1][tid >> 6] = q1; red[2][tid >> 6] = q2; }
    __syncthreads();
    if (tid == 0) {
      float d = red[0][0] + red[0][1] + red[0][2] + red[0][3];
      float a = red[1][0] + red[1][1] + red[1][2] + red[1][3];
      float c = red[2][0] + red[2][1] + red[2][2] + red[2][3];
      sims[p] = d / (sqrtf(a) * sqrtf(c) + EPSF);
    }
    __syncthreads();
  }
  if (tid < NC) {
    float v = out_b[tid];
#pragma unroll
    for (int k = 0; k < 3; ++k) v = fmaf(sims[k], out_w[k * NC + tid], v);
    out[b * NC + tid] = v;
  }
}

extern "C" void kernel_launch(void* const* d_in, const int* in_sizes, int n_in,
                              void* d_out, int out_size, void* d_ws, size_t ws_size,
                              hipStream_t stream) {
  const float* premise    = (const float*)d_in[0];
  const float* hypothesis = (const float*)d_in[1];
  const float* aW1        = (const float*)d_in[2];
  const float* conv1_w    = (const float*)d_in[3];
  const float* conv1_b    = (const float*)d_in[4];
  const float* aW2        = (const float*)d_in[5];
  const float* conv2_w    = (const float*)d_in[6];
  const float* conv2_b    = (const float*)d_in[7];
  const float* out_w      = (const float*)d_in[8];
  const float* out_b      = (const float*)d_in[9];
  float* out = (float*)d_out;

  float* ws = (float*)d_ws;
  size_t off = 0;
  auto alloc = [&](size_t n) { float* p = ws + off; off += n; return p; };
  float* wT1  = alloc((size_t)KW * 2 * D0 * H);   // 2,752,512
  float* wT2  = alloc((size_t)KW * 2 * H * H);    //   917,504
  float* LO0  = alloc((size_t)B * D0);
  float* RO0  = alloc((size_t)B * D0);
  float* LO1  = alloc((size_t)B * H);
  float* RO1  = alloc((size_t)B * H);
  float* LO2  = alloc((size_t)B * H);
  float* RO2  = alloc((size_t)B * H);
  float* la   = alloc((size_t)B * T70);
  float* ra   = alloc((size_t)B * T70);
  float* attb = alloc((size_t)B * S * S);         // reused layer1+layer2
  float* lcT  = alloc((size_t)B * T70 * H);       // reused as lc2
  float* rcT  = alloc((size_t)B * T70 * H);       // reused as rc2
  float* LI1  = alloc((size_t)B * S * H);
  float* RI1  = alloc((size_t)B * S * H);
  float* x1a  = alloc((size_t)B * S * D0);        // layer2 x1a2 aliases prefix
  float* x2a  = alloc((size_t)B * S * D0);
  // total ~25.9M floats ~104 MB

  // 1. weight transposes
  k_transpose_w<<<(KW*2*D0*H + 255)/256, 256, 0, stream>>>(conv1_w, wT1, D0);
  k_transpose_w<<<(KW*2*H*H  + 255)/256, 256, 0, stream>>>(conv2_w, wT2, H);
  // 2. LO0/RO0
  k_mean_rows<<<(B*D0 + 255)/256, 256, 0, stream>>>(premise,    LO0, S, D0, 1.f/S);
  k_mean_rows<<<(B*D0 + 255)/256, 256, 0, stream>>>(hypothesis, RO0, S, D0, 1.f/S);
  // 3. att1
  k_att<S, D0, true, false><<<B, 256, 0, stream>>>(premise, hypothesis, attb, nullptr, nullptr);
  // 4. x1a/x2a
  k_xa<D0><<<B, 256, 0, stream>>>(attb, aW1, x1a, x2a);
  // 5. conv1 (fused bias+tanh) -> lcT, rcT  [B,70,H]
  dim3 cgrid(H/64, (B*T70)/64);
  k_conv<D0><<<cgrid, 256, 0, stream>>>(premise,    x1a, wT1, conv1_b, lcT);
  k_conv<D0><<<cgrid, 256, 0, stream>>>(hypothesis, x2a, wT1, conv1_b, rcT);
  // 6. att2 -> row/col sums only
  k_att<T70, H, false, true><<<B, 256, 0, stream>>>(lcT, rcT, nullptr, la, ra);
  // 7. LO1/RO1 (all-pool)
  k_mean_rows<<<(B*H + 255)/256, 256, 0, stream>>>(lcT, LO1, T70, H, 1.f/T70);
  k_mean_rows<<<(B*H + 255)/256, 256, 0, stream>>>(rcT, RO1, T70, H, 1.f/T70);
  // 8. w_pool -> LI1/RI1  [B,64,H]
  k_wpool<<<(B*S*H + 255)/256, 256, 0, stream>>>(lcT, la, LI1);
  k_wpool<<<(B*S*H + 255)/256, 256, 0, stream>>>(rcT, ra, RI1);
  // 9. layer-2 attention
  k_att<S, H, true, false><<<B, 256, 0, stream>>>(LI1, RI1, attb, nullptr, nullptr);
  // 10. layer-2 xa (aliases x1a/x2a prefix)
  k_xa<H><<<B, 256, 0, stream>>>(attb, aW2, x1a, x2a);
  // 11. conv2 -> reuse lcT/rcT
  k_conv<H><<<cgrid, 256, 0, stream>>>(LI1, x1a, wT2, conv2_b, lcT);
  k_conv<H><<<cgrid, 256, 0, stream>>>(RI1, x2a, wT2, conv2_b, rcT);
  // 12. LO2/RO2
  k_mean_rows<<<(B*H + 255)/256, 256, 0, stream>>>(lcT, LO2, T70, H, 1.f/T70);
  k_mean_rows<<<(B*H + 255)/256, 256, 0, stream>>>(rcT, RO2, T70, H, 1.f/T70);
  // 13. cosine sims + logits
  k_final<<<B, 256, 0, stream>>>(LO0, RO0, LO1, RO1, LO2, RO2, out_w, out_b, out);
}

// Round 2
// 974.234 us; speedup vs baseline: 5.4528x; 5.4528x over previous
//
#include <hip/hip_runtime.h>
#include <math.h>

typedef _Float16 f16;
typedef _Float16 half8 __attribute__((ext_vector_type(8)));
typedef _Float16 half4 __attribute__((ext_vector_type(4)));
typedef float floatx4 __attribute__((ext_vector_type(4)));

constexpr int B   = 128;
constexpr int S   = 64;
constexpr int D0  = 768;
constexpr int H   = 256;
constexpr int KW  = 7;
constexpr int NC  = 3;
constexpr int T70 = S + KW - 1;  // 70
constexpr float EPSF = 1e-12f;

// ---------- fp32 -> fp16 convert (vectorized) ----------
__global__ __launch_bounds__(256) void k_cvt(const float* __restrict__ in,
                                             f16* __restrict__ out, int n4) {
  int i = blockIdx.x * 256 + threadIdx.x;
  if (i >= n4) return;
  float4 v = reinterpret_cast<const float4*>(in)[i];
  half4 o = {(f16)v.x, (f16)v.y, (f16)v.z, (f16)v.w};
  reinterpret_cast<half4*>(out)[i] = o;
}

// ---------- conv weight transpose: cw[d,7,2,H] -> wTT[h][(k*2+c)*d+dd] fp16 ----------
__global__ __launch_bounds__(256) void k_trw(const float* __restrict__ cw,
                                             f16* __restrict__ wTT, int DPC, int Ktot) {
  __shared__ f16 tile[64][65];
  const int kc = blockIdx.z, k = kc >> 1, c = kc & 1;
  const int dd0 = blockIdx.x * 64, h0 = blockIdx.y * 64;
  const int tx = threadIdx.x & 63, ty = threadIdx.x >> 6;
#pragma unroll
  for (int i = 0; i < 64; i += 4) {
    int dd = dd0 + i + ty;
    tile[i + ty][tx] = (f16)cw[(size_t)((dd * KW + k) * 2 + c) * H + h0 + tx];
  }
  __syncthreads();
#pragma unroll
  for (int i = 0; i < 64; i += 4) {
    int h = h0 + i + ty;
    wTT[(size_t)h * Ktot + (size_t)kc * DPC + dd0 + tx] = tile[tx][i + ty];
  }
}

// ---------- mean over axis 1 of [B,T,F] fp32 -> [B,F] ----------
__global__ __launch_bounds__(256) void k_mean_rows(const float* __restrict__ x,
                                                   float* __restrict__ out,
                                                   int T, int F, float inv) {
  int idx = blockIdx.x * 256 + threadIdx.x;
  if (idx >= B * F) return;
  int b = idx / F, f = idx % F;
  const float* p = x + (size_t)b * T * F + f;
  float s = 0.f;
  for (int t = 0; t < T; ++t) s += p[(size_t)t * F];
  out[idx] = s * inv;
}

// ---------- attention matrix 1/(1+sqrt(max(|xi|^2+|xj|^2-2xi.xj,0)+eps)) ----------
template<int W, int D, bool STORE, bool SUMS, typename T>
__global__ __launch_bounds__(256) void k_att(const T* __restrict__ X1,
                                             const T* __restrict__ X2,
                                             float* __restrict__ att,
                                             float* __restrict__ la,
                                             float* __restrict__ ra) {
  constexpr int Wp = (W <= 64) ? 64 : 80;
  constexpr int TI = Wp / 16;
  constexpr int KT = 32;
  __shared__ float As[KT][Wp + 1];
  __shared__ float Bs[KT][Wp + 1];
  __shared__ float n1s[Wp];
  __shared__ float n2s[Wp];
  __shared__ float att_s[SUMS ? (W * W) : 1];

  const int b = blockIdx.x;
  const int tid = threadIdx.x;
  const T* __restrict__ x1 = X1 + (size_t)b * W * D;
  const T* __restrict__ x2 = X2 + (size_t)b * W * D;

  const int ty = tid >> 4, tx = tid & 15;
  const int i0 = ty * TI, j0 = tx * TI;

  float acc[TI][TI];
#pragma unroll
  for (int ii = 0; ii < TI; ++ii)
#pragma unroll
    for (int jj = 0; jj < TI; ++jj) acc[ii][jj] = 0.f;
  float na1 = 0.f, na2 = 0.f;

  for (int kk0 = 0; kk0 < D; kk0 += KT) {
    __syncthreads();
    for (int idx = tid; idx < Wp * KT; idx += 256) {
      const int i = idx >> 5, kk = idx & 31;
      float v1 = 0.f, v2 = 0.f;
      if (i < W) {
        v1 = (float)x1[(size_t)i * D + kk0 + kk];
        v2 = (float)x2[(size_t)i * D + kk0 + kk];
      }
      As[kk][i] = v1;
      Bs[kk][i] = v2;
    }
    __syncthreads();
#pragma unroll
    for (int kk = 0; kk < KT; ++kk) {
      float a[TI], bb[TI];
#pragma unroll
      for (int ii = 0; ii < TI; ++ii) a[ii] = As[kk][i0 + ii];
#pragma unroll
      for (int jj = 0; jj < TI; ++jj) bb[jj] = Bs[kk][j0 + jj];
#pragma unroll
      for (int ii = 0; ii < TI; ++ii)
#pragma unroll
        for (int jj = 0; jj < TI; ++jj)
          acc[ii][jj] = fmaf(a[ii], bb[jj], acc[ii][jj]);
    }
    if (tid < W) {
#pragma unroll
      for (int kk = 0; kk < KT; ++kk) { float v = As[kk][tid]; na1 = fmaf(v, v, na1); }
    }
    if (tid >= 128 && tid < 128 + W) {
#pragma unroll
      for (int kk = 0; kk < KT; ++kk) { float v = Bs[kk][tid - 128]; na2 = fmaf(v, v, na2); }
    }
  }
  if (tid < W) n1s[tid] = na1;
  if (tid >= 128 && tid < 128 + W) n2s[tid - 128] = na2;
  __syncthreads();

#pragma unroll
  for (int ii = 0; ii < TI; ++ii) {
    const int i = i0 + ii;
#pragma unroll
    for (int jj = 0; jj < TI; ++jj) {
      const int j = j0 + jj;
      if (i < W && j < W) {
        float sq = n1s[i] + n2s[j] - 2.f * acc[ii][jj];
        sq = fmaxf(sq, 0.f);
        const float v = 1.f / (1.f + sqrtf(sq + EPSF));
        if (STORE) att[((size_t)b * W + i) * W + j] = v;
        if (SUMS)  att_s[i * W + j] = v;
      }
    }
  }
  if (SUMS) {
    __syncthreads();
    if (tid < W) {
      float sum = 0.f;
      for (int j = 0; j < W; ++j) sum += att_s[tid * W + j];
      la[b * W + tid] = sum;
    }
    if (tid >= 128 && tid < 128 + W) {
      const int j = tid - 128;
      float sum = 0.f;
      for (int i = 0; i < W; ++i) sum += att_s[i * W + j];
      ra[b * W + j] = sum;
    }
  }
}

// ---------- x1a[b,i,d]=sum_j att[b,i,j]*aW[j,d]; x2a[b,i,d]=sum_j att[b,j,i]*aW[j,d] -> fp16 ----------
template<int D>
__global__ __launch_bounds__(256) void k_xa(const float* __restrict__ att,
                                            const float* __restrict__ aW,
                                            f16* __restrict__ x1a,
                                            f16* __restrict__ x2a) {
  __shared__ float a_s[S][S];
  const int b = blockIdx.x;
  const int tid = threadIdx.x;
  for (int idx = tid; idx < S * S; idx += 256)
    a_s[idx >> 6][idx & 63] = att[(size_t)b * S * S + idx];
  __syncthreads();
  for (int i0 = 0; i0 < S; i0 += 8) {
    for (int d0 = 0; d0 < D; d0 += 256) {
      const int d = d0 + tid;
      float acc1[8] = {0.f,0.f,0.f,0.f,0.f,0.f,0.f,0.f};
      float acc2[8] = {0.f,0.f,0.f,0.f,0.f,0.f,0.f,0.f};
      for (int j = 0; j < S; ++j) {
        const float w = aW[(size_t)j * D + d];
#pragma unroll
        for (int ii = 0; ii < 8; ++ii) {
          acc1[ii] = fmaf(a_s[i0 + ii][j], w, acc1[ii]);
          acc2[ii] = fmaf(a_s[j][i0 + ii], w, acc2[ii]);
        }
      }
#pragma unroll
      for (int ii = 0; ii < 8; ++ii) {
        x1a[((size_t)b * S + i0 + ii) * D + d] = (f16)acc1[ii];
        x2a[((size_t)b * S + i0 + ii) * D + d] = (f16)acc2[ii];
      }
    }
  }
}

// ---------- conv as im2col MFMA GEMM (fp16 in, fp32 acc), fused bias+tanh ----------
// outT[m=b*70+t][h] = tanh(cb[h] + sum_{kc,dd} src_{kc&1}[b, t+(kc>>1)-6, dd] * wTT[h][kc*DPC+dd])
// Tile: BM=64 x BN=128, BK=32. 4 waves (2x2), wave tile 32x64 (2x4 MFMA frags).
// LDS stored as 16B chunks with XOR swizzle chunk^=(row&3): conflict-free on write+read.
template<int DPC>
__global__ __launch_bounds__(256) void k_conv(const f16* __restrict__ X,
                                              const f16* __restrict__ XA,
                                              const f16* __restrict__ wTT,
                                              const float* __restrict__ bias,
                                              float* __restrict__ outT) {
  constexpr int NDQ = DPC / 32;
  constexpr int NSTEP = 14 * NDQ;
  constexpr int KTOT = 14 * DPC;
  __shared__ half8 A8[2][64 * 4];   // [buf][row*4 + swz_chunk]
  __shared__ half8 B8[2][128 * 4];

  const int tid = threadIdx.x;
  const int n0 = blockIdx.x * 128;
  const int m0 = blockIdx.y * 64;
  const int lane = tid & 63;
  const int wave = tid >> 6;
  const int wr = wave >> 1, wc = wave & 1;
  const int l15 = lane & 15, g = lane >> 4;

  // staging thread roles
  const int ar = tid >> 2, ac = tid & 3;   // A: row 0..63, chunk 0..3
  const int br = tid >> 1, bc = tid & 1;   // B: row 0..127, chunks {bc, bc+2}
  const int m = m0 + ar;
  const int bnum = m / T70;
  const int tt = m - bnum * T70;
  const size_t xrow = (size_t)bnum * S * DPC + (size_t)ac * 8;
  const f16* __restrict__ bp0 = wTT + (size_t)(n0 + br) * KTOT + (size_t)bc * 8;

  floatx4 acc[2][4];
#pragma unroll
  for (int i = 0; i < 2; ++i)
#pragma unroll
    for (int j = 0; j < 4; ++j) acc[i][j] = (floatx4)0.f;

  half8 aR, bR0, bR1;
  auto load_tile = [&](int kc, int dq) {
    const int s = tt - (KW - 1) + (kc >> 1);
    const bool ok = (s >= 0) && (s < S);
    const f16* src = (kc & 1) ? XA : X;
    const f16* ap = src + xrow + (size_t)(ok ? s : 0) * DPC + dq * 32;
    aR = *reinterpret_cast<const half8*>(ap);
    if (!ok) aR = (half8)(f16)0.f;
    const f16* bp = bp0 + (size_t)kc * DPC + dq * 32;
    bR0 = *reinterpret_cast<const half8*>(bp);
    bR1 = *reinterpret_cast<const half8*>(bp + 16);
  };
  auto store_tile = [&](int buf) {
    A8[buf][ar * 4 + (ac ^ (ar & 3))] = aR;
    B8[buf][br * 4 + (bc ^ (br & 3))] = bR0;
    B8[buf][br * 4 + ((bc + 2) ^ (br & 3))] = bR1;
  };
  auto compute = [&](int buf) {
    half8 af[2], bf[4];
#pragma unroll
    for (int i = 0; i < 2; ++i) {
      const int row = wr * 32 + i * 16 + l15;
      af[i] = A8[buf][row * 4 + (g ^ (row & 3))];
    }
#pragma unroll
    for (int j = 0; j < 4; ++j) {
      const int row = wc * 64 + j * 16 + l15;
      bf[j] = B8[buf][row * 4 + (g ^ (row & 3))];
    }
#pragma unroll
    for (int i = 0; i < 2; ++i)
#pragma unroll
      for (int j = 0; j < 4; ++j)
        acc[i][j] = __builtin_amdgcn_mfma_f32_16x16x32_f16(af[i], bf[j], acc[i][j], 0, 0, 0);
  };

  load_tile(0, 0);
  store_tile(0);
  __syncthreads();
  int kc = 0, dq = 1;
  for (int ks = 0; ks < NSTEP; ++ks) {
    const int buf = ks & 1;
    const bool more = (ks + 1 < NSTEP);
    if (more) load_tile(kc, dq);     // global loads in flight over compute
    compute(buf);
    if (more) store_tile(buf ^ 1);   // compiler waits vmcnt before ds_write
    __syncthreads();                 // single barrier per K-step
    if (more) { if (++dq == NDQ) { dq = 0; ++kc; } }
  }

  // epilogue: C/D frag col=lane&15, row=(lane>>4)*4+reg
#pragma unroll
  for (int i = 0; i < 2; ++i) {
    const int mr = m0 + wr * 32 + i * 16 + g * 4;
#pragma unroll
    for (int j = 0; j < 4; ++j) {
      const int h = n0 + wc * 64 + j * 16 + l15;
      const float bv = bias[h];
#pragma unroll
      for (int r = 0; r < 4; ++r)
        outT[(size_t)(mr + r) * H + h] = tanhf(acc[i][j][r] + bv);
    }
  }
}

// ---------- attention-weighted window pool -> fp16: out[b,s,h]=sum_{j<7} xc[b,s+j,h]*a[b,s+j] ----------
__global__ __launch_bounds__(256) void k_wpool(const float* __restrict__ xc,
                                               const float* __restrict__ a,
                                               f16* __restrict__ out) {
  int idx = blockIdx.x * 256 + threadIdx.x;
  if (idx >= B * S * H) return;
  int h = idx & (H - 1);
  int rest = idx >> 8;
  int s = rest & (S - 1), b = rest >> 6;
  const float* xp = xc + ((size_t)b * T70 + s) * H + h;
  const float* ap = a + b * T70 + s;
  float acc = 0.f;
#pragma unroll
  for (int j = 0; j < KW; ++j) acc = fmaf(xp[(size_t)j * H], ap[j], acc);
  out[idx] = (f16)acc;
}

// ---------- cosine sims + final tiny GEMM ----------
__global__ __launch_bounds__(256) void k_final(const float* __restrict__ LO0,
                                               const float* __restrict__ RO0,
                                               const float* __restrict__ LO1,
                                               const float* __restrict__ RO1,
                                               const float* __restrict__ LO2,
                                               const float* __restrict__ RO2,
                                               const float* __restrict__ out_w,
                                               const float* __restrict__ out_b,
                                               float* __restrict__ out) {
  const int b = blockIdx.x;
  const int tid = threadIdx.x;
  __shared__ float red[3][4];
  __shared__ float sims[3];
  const float* Ls[3] = {LO0 + (size_t)b * D0, LO1 + (size_t)b * H, LO2 + (size_t)b * H};
  const float* Rs[3] = {RO0 + (size_t)b * D0, RO1 + (size_t)b * H, RO2 + (size_t)b * H};
  const int dims[3] = {D0, H, H};
#pragma unroll
  for (int p = 0; p < 3; ++p) {
    float dot = 0.f, q1 = 0.f, q2 = 0.f;
    for (int i = tid; i < dims[p]; i += 256) {
      const float v1 = Ls[p][i], v2 = Rs[p][i];
      dot = fmaf(v1, v2, dot);
      q1  = fmaf(v1, v1, q1);
      q2  = fmaf(v2, v2, q2);
    }
#pragma unroll
    for (int off = 32; off > 0; off >>= 1) {
      dot += __shfl_down(dot, off);
      q1  += __shfl_down(q1, off);
      q2  += __shfl_down(q2, off);
    }
    if ((tid & 63) == 0) { red[0][tid >> 6] = dot; red[1][tid >> 6] = q1; red[2][tid >> 6] = q2; }
    __syncthreads();
    if (tid == 0) {
      float d = red[0][0] + red[0][1] + red[0][2] + red[0][3];
      float a = red[1][0] + red[1][1] + red[1][2] + red[1][3];
      float c = red[2][0] + red[2][1] + red[2][2] + red[2][3];
      sims[p] = d / (sqrtf(a) * sqrtf(c) + EPSF);
    }
    __syncthreads();
  }
  if (tid < NC) {
    float v = out_b[tid];
#pragma unroll
    for (int k = 0; k < 3; ++k) v = fmaf(sims[k], out_w[k * NC + tid], v);
    out[b * NC + tid] = v;
  }
}

extern "C" void kernel_launch(void* const* d_in, const int* in_sizes, int n_in,
                              void* d_out, int out_size, void* d_ws, size_t ws_size,
                              hipStream_t stream) {
  const float* premise    = (const float*)d_in[0];
  const float* hypothesis = (const float*)d_in[1];
  const float* aW1        = (const float*)d_in[2];
  const float* conv1_w    = (const float*)d_in[3];
  const float* conv1_b    = (const float*)d_in[4];
  const float* aW2        = (const float*)d_in[5];
  const float* conv2_w    = (const float*)d_in[6];
  const float* conv2_b    = (const float*)d_in[7];
  const float* out_w      = (const float*)d_in[8];
  const float* out_b      = (const float*)d_in[9];
  float* out = (float*)d_out;

  char* ws = (char*)d_ws;
  size_t off = 0;
  auto alloc = [&](size_t bytes) {
    void* p = ws + off;
    off += (bytes + 255) & ~(size_t)255;
    return p;
  };
  f16*   wTT1  = (f16*)alloc((size_t)14 * D0 * H * 2);       // 5.5 MB
  f16*   wTT2  = (f16*)alloc((size_t)14 * H * H * 2);        // 1.8 MB
  f16*   Xh    = (f16*)alloc((size_t)B * S * D0 * 2);        // 12.6 MB
  f16*   Yh    = (f16*)alloc((size_t)B * S * D0 * 2);
  f16*   x1ah  = (f16*)alloc((size_t)B * S * D0 * 2);        // layer2 x1a2h aliases prefix
  f16*   x2ah  = (f16*)alloc((size_t)B * S * D0 * 2);
  f16*   LI1h  = (f16*)alloc((size_t)B * S * H * 2);         // 4.2 MB
  f16*   RI1h  = (f16*)alloc((size_t)B * S * H * 2);
  float* lcT   = (float*)alloc((size_t)B * T70 * H * 4);     // 9.2 MB (reused layer2)
  float* rcT   = (float*)alloc((size_t)B * T70 * H * 4);
  float* attb  = (float*)alloc((size_t)B * S * S * 4);       // 2.1 MB (reused)
  float* LO0   = (float*)alloc((size_t)B * D0 * 4);
  float* RO0   = (float*)alloc((size_t)B * D0 * 4);
  float* LO1   = (float*)alloc((size_t)B * H * 4);
  float* RO1   = (float*)alloc((size_t)B * H * 4);
  float* LO2   = (float*)alloc((size_t)B * H * 4);
  float* RO2   = (float*)alloc((size_t)B * H * 4);
  float* la    = (float*)alloc((size_t)B * T70 * 4);
  float* ra    = (float*)alloc((size_t)B * T70 * 4);
  f16*   x1a2h = x1ah;   // alias: layer-1 x1ah fully consumed by conv1 before reuse
  f16*   x2a2h = x2ah;
  // total ~88 MB

  const int n4 = B * S * D0 / 4;
  // 0. fp16 converts + weight transposes
  k_cvt<<<(n4 + 255) / 256, 256, 0, stream>>>(premise, Xh, n4);
  k_cvt<<<(n4 + 255) / 256, 256, 0, stream>>>(hypothesis, Yh, n4);
  k_trw<<<dim3(D0 / 64, H / 64, 14), 256, 0, stream>>>(conv1_w, wTT1, D0, 14 * D0);
  k_trw<<<dim3(H / 64,  H / 64, 14), 256, 0, stream>>>(conv2_w, wTT2, H, 14 * H);
  // 1. LO0/RO0
  k_mean_rows<<<(B * D0 + 255) / 256, 256, 0, stream>>>(premise,    LO0, S, D0, 1.f / S);
  k_mean_rows<<<(B * D0 + 255) / 256, 256, 0, stream>>>(hypothesis, RO0, S, D0, 1.f / S);
  // 2. att1 + x1a/x2a (fp16)
  k_att<S, D0, true, false, float><<<B, 256, 0, stream>>>(premise, hypothesis, attb, nullptr, nullptr);
  k_xa<D0><<<B, 256, 0, stream>>>(attb, aW1, x1ah, x2ah);
  // 3. conv1 (MFMA, fused bias+tanh) -> lcT, rcT  [B*70, H] fp32
  dim3 cgrid(2, (B * T70) / 64);
  k_conv<D0><<<cgrid, 256, 0, stream>>>(Xh, x1ah, wTT1, conv1_b, lcT);
  k_conv<D0><<<cgrid, 256, 0, stream>>>(Yh, x2ah, wTT1, conv1_b, rcT);
  // 4. att2 row/col sums
  k_att<T70, H, false, true, float><<<B, 256, 0, stream>>>(lcT, rcT, nullptr, la, ra);
  // 5. LO1/RO1
  k_mean_rows<<<(B * H + 255) / 256, 256, 0, stream>>>(lcT, LO1, T70, H, 1.f / T70);
  k_mean_rows<<<(B * H + 255) / 256, 256, 0, stream>>>(rcT, RO1, T70, H, 1.f / T70);
  // 6. w_pool -> LI1h/RI1h (fp16)
  k_wpool<<<(B * S * H + 255) / 256, 256, 0, stream>>>(lcT, la, LI1h);
  k_wpool<<<(B * S * H + 255) / 256, 256, 0, stream>>>(rcT, ra, RI1h);
  // 7. layer-2 attention (fp16 inputs) + xa
  k_att<S, H, true, false, f16><<<B, 256, 0, stream>>>(LI1h, RI1h, attb, nullptr, nullptr);
  k_xa<H><<<B, 256, 0, stream>>>(attb, aW2, x1a2h, x2a2h);
  // 8. conv2 -> reuse lcT/rcT
  k_conv<H><<<cgrid, 256, 0, stream>>>(LI1h, x1a2h, wTT2, conv2_b, lcT);
  k_conv<H><<<cgrid, 256, 0, stream>>>(RI1h, x2a2h, wTT2, conv2_b, rcT);
  // 9. LO2/RO2
  k_mean_rows<<<(B * H + 255) / 256, 256, 0, stream>>>(lcT, LO2, T70, H, 1.f / T70);
  k_mean_rows<<<(B * H + 255) / 256, 256, 0, stream>>>(rcT, RO2, T70, H, 1.f / T70);
  // 10. cosine sims + logits
  k_final<<<B, 256, 0, stream>>>(LO0, RO0, LO1, RO1, LO2, RO2, out_w, out_b, out);
}

// Round 3
// 455.312 us; speedup vs baseline: 11.6674x; 2.1397x over previous
//
#include <hip/hip_runtime.h>
#include <math.h>

typedef _Float16 f16;
typedef _Float16 half8 __attribute__((ext_vector_type(8)));
typedef _Float16 half4 __attribute__((ext_vector_type(4)));
typedef float floatx4 __attribute__((ext_vector_type(4)));

constexpr int B   = 128;
constexpr int S   = 64;
constexpr int D0  = 768;
constexpr int H   = 256;
constexpr int KW  = 7;
constexpr int NC  = 3;
constexpr int T70 = S + KW - 1;  // 70
constexpr float EPSF = 1e-12f;

// ---------- fp32 -> fp16 convert ----------
__global__ __launch_bounds__(256) void k_cvt(const float* __restrict__ in,
                                             f16* __restrict__ out, int n4) {
  int i = blockIdx.x * 256 + threadIdx.x;
  if (i >= n4) return;
  float4 v = reinterpret_cast<const float4*>(in)[i];
  half4 o = {(f16)v.x, (f16)v.y, (f16)v.z, (f16)v.w};
  reinterpret_cast<half4*>(out)[i] = o;
}

// ---------- conv weight transpose: cw[d,7,2,H] -> wTT[h][(k*2+c)*d+dd] fp16 ----------
__global__ __launch_bounds__(256) void k_trw(const float* __restrict__ cw,
                                             f16* __restrict__ wTT, int DPC, int Ktot) {
  __shared__ f16 tile[64][65];
  const int kc = blockIdx.z, k = kc >> 1, c = kc & 1;
  const int dd0 = blockIdx.x * 64, h0 = blockIdx.y * 64;
  const int tx = threadIdx.x & 63, ty = threadIdx.x >> 6;
#pragma unroll
  for (int i = 0; i < 64; i += 4) {
    int dd = dd0 + i + ty;
    tile[i + ty][tx] = (f16)cw[(size_t)((dd * KW + k) * 2 + c) * H + h0 + tx];
  }
  __syncthreads();
#pragma unroll
  for (int i = 0; i < 64; i += 4) {
    int h = h0 + i + ty;
    wTT[(size_t)h * Ktot + (size_t)kc * DPC + dd0 + tx] = tile[tx][i + ty];
  }
}

// ---------- aW[S=64][D] fp32 -> aWT[D][64] fp16 ----------
__global__ __launch_bounds__(256) void k_trw_aw(const float* __restrict__ aW,
                                                f16* __restrict__ aWT, int D) {
  __shared__ f16 tile[64][65];
  const int d0 = blockIdx.x * 64;
  const int tx = threadIdx.x & 63, ty = threadIdx.x >> 6;
#pragma unroll
  for (int i = 0; i < 64; i += 4) {
    int s = i + ty;
    tile[s][tx] = (f16)aW[(size_t)s * D + d0 + tx];
  }
  __syncthreads();
#pragma unroll
  for (int i = 0; i < 64; i += 4) {
    int d = i + ty;
    aWT[(size_t)(d0 + d) * 64 + tx] = tile[tx][d];
  }
}

// ---------- mean over axis 1 of [B,T,F] -> [B,F] fp32 ----------
template<typename T>
__global__ __launch_bounds__(256) void k_mean(const T* __restrict__ x,
                                              float* __restrict__ out,
                                              int Tr, int F, float inv) {
  int idx = blockIdx.x * 256 + threadIdx.x;
  if (idx >= B * F) return;
  int b = idx / F, f = idx % F;
  const T* p = x + (size_t)b * Tr * F + f;
  float s = 0.f;
  for (int t = 0; t < Tr; ++t) s += (float)p[(size_t)t * F];
  out[idx] = s * inv;
}

// ---------- MFMA attention: att[i][j] = 1/(1+sqrt(max(n1+n2-2*x1_i.x2_j,0)+eps)) ----------
// X1,X2: [B,W,D] fp16. STORE: write att fp16 + att^T fp16. SUMS: write row sums la, col sums ra.
template<int W, int WP, int D, bool STORE, bool SUMS>
__global__ __launch_bounds__(256) void k_att(const f16* __restrict__ X1,
                                             const f16* __restrict__ X2,
                                             f16* __restrict__ attA,
                                             f16* __restrict__ attT,
                                             float* __restrict__ la,
                                             float* __restrict__ ra) {
  constexpr int FR = WP / 32;   // frags per wave dim (4 waves as 2x2, wave tile 16FR x 16FR)
  __shared__ half8 As[WP * 4];
  __shared__ half8 Bs[WP * 4];
  __shared__ float n1s[WP], n2s[WP];
  __shared__ float att_s[SUMS ? WP * (WP + 1) : 1];

  const int b = blockIdx.x, tid = threadIdx.x;
  const int lane = tid & 63, wave = tid >> 6;
  const int wr = wave >> 1, wc = wave & 1;
  const int l15 = lane & 15, g = lane >> 4;
  const f16* __restrict__ x1 = X1 + (size_t)b * W * D;
  const f16* __restrict__ x2 = X2 + (size_t)b * W * D;

  floatx4 acc[FR][FR];
#pragma unroll
  for (int i = 0; i < FR; ++i)
#pragma unroll
    for (int j = 0; j < FR; ++j) acc[i][j] = (floatx4)0.f;
  float na1 = 0.f, na2 = 0.f;

  for (int k0 = 0; k0 < D; k0 += 32) {
    __syncthreads();
    for (int u = tid; u < WP * 4; u += 256) {
      const int r = u >> 2, c = u & 3;
      half8 v1 = (half8)(f16)0.f, v2 = (half8)(f16)0.f;
      if (r < W) {
        v1 = *reinterpret_cast<const half8*>(x1 + (size_t)r * D + k0 + c * 8);
        v2 = *reinterpret_cast<const half8*>(x2 + (size_t)r * D + k0 + c * 8);
      }
      const int p = r * 4 + (c ^ ((r >> 1) & 3));
      As[p] = v1;
      Bs[p] = v2;
    }
    __syncthreads();
    half8 af[FR], bf[FR];
#pragma unroll
    for (int fi = 0; fi < FR; ++fi) {
      const int row = wr * 16 * FR + fi * 16 + l15;
      af[fi] = As[row * 4 + (g ^ ((row >> 1) & 3))];
    }
#pragma unroll
    for (int fj = 0; fj < FR; ++fj) {
      const int row = wc * 16 * FR + fj * 16 + l15;
      bf[fj] = Bs[row * 4 + (g ^ ((row >> 1) & 3))];
    }
#pragma unroll
    for (int fi = 0; fi < FR; ++fi)
#pragma unroll
      for (int fj = 0; fj < FR; ++fj)
        acc[fi][fj] = __builtin_amdgcn_mfma_f32_16x16x32_f16(af[fi], bf[fj], acc[fi][fj], 0, 0, 0);
    // norms
    if (tid < WP) {
      const int r = tid;
#pragma unroll
      for (int c = 0; c < 4; ++c) {
        half8 v = As[r * 4 + (c ^ ((r >> 1) & 3))];
#pragma unroll
        for (int e = 0; e < 8; ++e) { float f = (float)v[e]; na1 = fmaf(f, f, na1); }
      }
    } else if (tid >= 128 && tid < 128 + WP) {
      const int r = tid - 128;
#pragma unroll
      for (int c = 0; c < 4; ++c) {
        half8 v = Bs[r * 4 + (c ^ ((r >> 1) & 3))];
#pragma unroll
        for (int e = 0; e < 8; ++e) { float f = (float)v[e]; na2 = fmaf(f, f, na2); }
      }
    }
  }
  if (tid < WP) n1s[tid] = na1;
  if (tid >= 128 && tid < 128 + WP) n2s[tid - 128] = na2;
  __syncthreads();

#pragma unroll
  for (int fi = 0; fi < FR; ++fi)
#pragma unroll
    for (int fj = 0; fj < FR; ++fj)
#pragma unroll
      for (int r = 0; r < 4; ++r) {
        const int i = wr * 16 * FR + fi * 16 + g * 4 + r;
        const int j = wc * 16 * FR + fj * 16 + l15;
        if (i < W && j < W) {
          float sq = fmaxf(n1s[i] + n2s[j] - 2.f * acc[fi][fj][r], 0.f);
          const float v = 1.f / (1.f + sqrtf(sq + EPSF));
          if (STORE) {
            attA[((size_t)b * W + i) * W + j] = (f16)v;
            attT[((size_t)b * W + j) * W + i] = (f16)v;
          }
          if (SUMS) att_s[i * (WP + 1) + j] = v;
        }
      }
  if (SUMS) {
    __syncthreads();
    if (tid < W) {
      float sum = 0.f;
      for (int j = 0; j < W; ++j) sum += att_s[tid * (WP + 1) + j];
      la[b * W + tid] = sum;
    }
    if (tid >= 128 && tid < 128 + W) {
      const int j = tid - 128;
      float sum = 0.f;
      for (int i = 0; i < W; ++i) sum += att_s[i * (WP + 1) + j];
      ra[b * W + j] = sum;
    }
  }
}

// ---------- MFMA xa: x1a[i][d]=sum_j attA[i][j]*aWT[d][j]; x2a from attT ----------
// grid (D/128, B); block 256 = 4 waves 2x2; tile M=64(i) x N=128(d), K=64(j)
__global__ __launch_bounds__(256) void k_xa(const f16* __restrict__ attA,
                                            const f16* __restrict__ attT,
                                            const f16* __restrict__ aWT,
                                            f16* __restrict__ x1a,
                                            f16* __restrict__ x2a, int D) {
  __shared__ half8 As[64 * 8];
  __shared__ half8 Ts[64 * 8];
  __shared__ half8 Bs[128 * 8];
  const int b = blockIdx.y, d0 = blockIdx.x * 128;
  const int tid = threadIdx.x;
  const int lane = tid & 63, wave = tid >> 6;
  const int wr = wave >> 1, wc = wave & 1;
  const int l15 = lane & 15, g = lane >> 4;
  const int r0 = tid >> 3, c8 = tid & 7;

#pragma unroll
  for (int p = 0; p < 2; ++p) {
    const int r = r0 + p * 32;
    const int sw = r * 8 + (c8 ^ (r & 7));
    As[sw] = *reinterpret_cast<const half8*>(attA + ((size_t)b * 64 + r) * 64 + c8 * 8);
    Ts[sw] = *reinterpret_cast<const half8*>(attT + ((size_t)b * 64 + r) * 64 + c8 * 8);
  }
#pragma unroll
  for (int p = 0; p < 4; ++p) {
    const int r = r0 + p * 32;
    Bs[r * 8 + (c8 ^ (r & 7))] =
        *reinterpret_cast<const half8*>(aWT + (size_t)(d0 + r) * 64 + c8 * 8);
  }
  __syncthreads();

  floatx4 acc1[2][4], acc2[2][4];
#pragma unroll
  for (int i = 0; i < 2; ++i)
#pragma unroll
    for (int j = 0; j < 4; ++j) { acc1[i][j] = (floatx4)0.f; acc2[i][j] = (floatx4)0.f; }

#pragma unroll
  for (int ks = 0; ks < 2; ++ks) {
    half8 a1[2], a2[2], bf[4];
#pragma unroll
    for (int i = 0; i < 2; ++i) {
      const int row = wr * 32 + i * 16 + l15;
      const int ch = ks * 4 + g;
      a1[i] = As[row * 8 + (ch ^ (row & 7))];
      a2[i] = Ts[row * 8 + (ch ^ (row & 7))];
    }
#pragma unroll
    for (int j = 0; j < 4; ++j) {
      const int row = wc * 64 + j * 16 + l15;
      const int ch = ks * 4 + g;
      bf[j] = Bs[row * 8 + (ch ^ (row & 7))];
    }
#pragma unroll
    for (int i = 0; i < 2; ++i)
#pragma unroll
      for (int j = 0; j < 4; ++j) {
        acc1[i][j] = __builtin_amdgcn_mfma_f32_16x16x32_f16(a1[i], bf[j], acc1[i][j], 0, 0, 0);
        acc2[i][j] = __builtin_amdgcn_mfma_f32_16x16x32_f16(a2[i], bf[j], acc2[i][j], 0, 0, 0);
      }
  }
#pragma unroll
  for (int i = 0; i < 2; ++i)
#pragma unroll
    for (int j = 0; j < 4; ++j)
#pragma unroll
      for (int r = 0; r < 4; ++r) {
        const int m = wr * 32 + i * 16 + g * 4 + r;
        const int d = d0 + wc * 64 + j * 16 + l15;
        x1a[((size_t)b * S + m) * D + d] = (f16)acc1[i][j][r];
        x2a[((size_t)b * S + m) * D + d] = (f16)acc2[i][j][r];
      }
}

// ---------- conv as im2col MFMA GEMM, z-fused (premise+hypothesis), XCD-aware ----------
// grid = 560 blocks: xcd=bid&7 -> n0 panel (xcd>>2), (z, mblk) from slot.
// Tile 64x128, BK=64, double-buffered, swizzle unit = row*8 + (chunk ^ (row&7)).
template<int DPC>
__global__ __launch_bounds__(256) void k_conv(const f16* __restrict__ X0,
                                              const f16* __restrict__ X1v,
                                              const f16* __restrict__ XA0,
                                              const f16* __restrict__ XA1,
                                              const f16* __restrict__ wTT,
                                              const float* __restrict__ bias,
                                              float* __restrict__ O32_0,
                                              float* __restrict__ O32_1,
                                              f16* __restrict__ O16_0,
                                              f16* __restrict__ O16_1) {
  constexpr int QPK = DPC / 64;
  constexpr int NSTEP = 14 * QPK;
  constexpr int KTOT = 14 * DPC;
  __shared__ half8 A8[2][64 * 8];
  __shared__ half8 B8[2][128 * 8];

  const int tid = threadIdx.x;
  const int bid = blockIdx.x;
  const int xcd = bid & 7, slot = bid >> 3;
  const int n0 = (xcd >> 2) * 128;
  const int w = slot * 4 + (xcd & 3);
  const int z = w & 1, mblk = w >> 1;
  const int m0 = mblk * 64;
  const f16* __restrict__ Xs  = z ? X1v : X0;
  const f16* __restrict__ XAs = z ? XA1 : XA0;
  float* __restrict__ Out32 = z ? O32_1 : O32_0;
  f16*   __restrict__ Out16 = z ? O16_1 : O16_0;

  const int lane = tid & 63, wave = tid >> 6;
  const int wr = wave >> 1, wc = wave & 1;
  const int l15 = lane & 15, g = lane >> 4;
  const int r0 = tid >> 3, c8 = tid & 7;

  int ttv[2];
  size_t bov[2];
#pragma unroll
  for (int p = 0; p < 2; ++p) {
    const int m = m0 + r0 + p * 32;
    const int bn = m / T70;
    ttv[p] = m - bn * T70 - (KW - 1);
    bov[p] = (size_t)bn * S * DPC + (size_t)c8 * 8;
  }
  const f16* bpv[4];
#pragma unroll
  for (int p = 0; p < 4; ++p)
    bpv[p] = wTT + (size_t)(n0 + r0 + p * 32) * KTOT + (size_t)c8 * 8;

  floatx4 acc[2][4];
#pragma unroll
  for (int i = 0; i < 2; ++i)
#pragma unroll
    for (int j = 0; j < 4; ++j) acc[i][j] = (floatx4)0.f;

  half8 aR[2], bR[4];
  auto load_tile = [&](int ks) {
    const int kc = ks / QPK, dq = ks % QPK;
    const int koff = dq * 64;
    const int k = kc >> 1;
    const f16* __restrict__ src = (kc & 1) ? XAs : Xs;
#pragma unroll
    for (int p = 0; p < 2; ++p) {
      const int s = ttv[p] + k;
      if (s >= 0 && s < S)
        aR[p] = *reinterpret_cast<const half8*>(src + bov[p] + (size_t)s * DPC + koff);
      else
        aR[p] = (half8)(f16)0.f;
    }
#pragma unroll
    for (int p = 0; p < 4; ++p)
      bR[p] = *reinterpret_cast<const half8*>(bpv[p] + (size_t)kc * DPC + koff);
  };
  auto store_tile = [&](int buf) {
#pragma unroll
    for (int p = 0; p < 2; ++p) {
      const int r = r0 + p * 32;
      A8[buf][r * 8 + (c8 ^ (r & 7))] = aR[p];
    }
#pragma unroll
    for (int p = 0; p < 4; ++p) {
      const int r = r0 + p * 32;
      B8[buf][r * 8 + (c8 ^ (r & 7))] = bR[p];
    }
  };
  auto compute = [&](int buf) {
    half8 af[2][2], bf[4][2];
#pragma unroll
    for (int i = 0; i < 2; ++i)
#pragma unroll
      for (int sub = 0; sub < 2; ++sub) {
        const int row = wr * 32 + i * 16 + l15;
        const int ch = sub * 4 + g;
        af[i][sub] = A8[buf][row * 8 + (ch ^ (row & 7))];
      }
#pragma unroll
    for (int j = 0; j < 4; ++j)
#pragma unroll
      for (int sub = 0; sub < 2; ++sub) {
        const int row = wc * 64 + j * 16 + l15;
        const int ch = sub * 4 + g;
        bf[j][sub] = B8[buf][row * 8 + (ch ^ (row & 7))];
      }
#pragma unroll
    for (int sub = 0; sub < 2; ++sub)
#pragma unroll
      for (int i = 0; i < 2; ++i)
#pragma unroll
        for (int j = 0; j < 4; ++j)
          acc[i][j] = __builtin_amdgcn_mfma_f32_16x16x32_f16(af[i][sub], bf[j][sub], acc[i][j], 0, 0, 0);
  };

  load_tile(0);
  store_tile(0);
  __syncthreads();
  for (int ks = 0; ks < NSTEP; ++ks) {
    const int buf = ks & 1;
    const bool more = (ks + 1 < NSTEP);
    if (more) load_tile(ks + 1);
    compute(buf);
    if (more) store_tile(buf ^ 1);
    __syncthreads();
  }

#pragma unroll
  for (int i = 0; i < 2; ++i) {
    const int mr = m0 + wr * 32 + i * 16 + g * 4;
#pragma unroll
    for (int j = 0; j < 4; ++j) {
      const int h = n0 + wc * 64 + j * 16 + l15;
      const float bv = bias[h];
#pragma unroll
      for (int r = 0; r < 4; ++r) {
        const float t = tanhf(acc[i][j][r] + bv);
        Out32[(size_t)(mr + r) * H + h] = t;
        Out16[(size_t)(mr + r) * H + h] = (f16)t;
      }
    }
  }
}

// ---------- window pool: out[b,s,h] = sum_{j<7} xc[b,s+j,h]*a[b,s+j] -> fp16 ----------
__global__ __launch_bounds__(256) void k_wpool(const float* __restrict__ xc,
                                               const float* __restrict__ a,
                                               f16* __restrict__ out) {
  int idx = blockIdx.x * 256 + threadIdx.x;
  if (idx >= B * S * H) return;
  int h = idx & (H - 1);
  int rest = idx >> 8;
  int s = rest & (S - 1), b = rest >> 6;
  const float* xp = xc + ((size_t)b * T70 + s) * H + h;
  const float* ap = a + b * T70 + s;
  float acc = 0.f;
#pragma unroll
  for (int j = 0; j < KW; ++j) acc = fmaf(xp[(size_t)j * H], ap[j], acc);
  out[idx] = (f16)acc;
}

// ---------- cosine sims + final tiny GEMM ----------
__global__ __launch_bounds__(256) void k_final(const float* __restrict__ LO0,
                                               const float* __restrict__ RO0,
                                               const float* __restrict__ LO1,
                                               const float* __restrict__ RO1,
                                               const float* __restrict__ LO2,
                                               const float* __restrict__ RO2,
                                               const float* __restrict__ out_w,
                                               const float* __restrict__ out_b,
                                               float* __restrict__ out) {
  const int b = blockIdx.x;
  const int tid = threadIdx.x;
  __shared__ float red[3][4];
  __shared__ float sims[3];
  const float* Ls[3] = {LO0 + (size_t)b * D0, LO1 + (size_t)b * H, LO2 + (size_t)b * H};
  const float* Rs[3] = {RO0 + (size_t)b * D0, RO1 + (size_t)b * H, RO2 + (size_t)b * H};
  const int dims[3] = {D0, H, H};
#pragma unroll
  for (int p = 0; p < 3; ++p) {
    float dot = 0.f, q1 = 0.f, q2 = 0.f;
    for (int i = tid; i < dims[p]; i += 256) {
      const float v1 = Ls[p][i], v2 = Rs[p][i];
      dot = fmaf(v1, v2, dot);
      q1  = fmaf(v1, v1, q1);
      q2  = fmaf(v2, v2, q2);
    }
#pragma unroll
    for (int off = 32; off > 0; off >>= 1) {
      dot += __shfl_down(dot, off);
      q1  += __shfl_down(q1, off);
      q2  += __shfl_down(q2, off);
    }
    if ((tid & 63) == 0) { red[0][tid >> 6] = dot; red[1][tid >> 6] = q1; red[2][tid >> 6] = q2; }
    __syncthreads();
    if (tid == 0) {
      float d = red[0][0] + red[0][1] + red[0][2] + red[0][3];
      float a = red[1][0] + red[1][1] + red[1][2] + red[1][3];
      float c = red[2][0] + red[2][1] + red[2][2] + red[2][3];
      sims[p] = d / (sqrtf(a) * sqrtf(c) + EPSF);
    }
    __syncthreads();
  }
  if (tid < NC) {
    float v = out_b[tid];
#pragma unroll
    for (int k = 0; k < 3; ++k) v = fmaf(sims[k], out_w[k * NC + tid], v);
    out[b * NC + tid] = v;
  }
}

extern "C" void kernel_launch(void* const* d_in, const int* in_sizes, int n_in,
                              void* d_out, int out_size, void* d_ws, size_t ws_size,
                              hipStream_t stream) {
  const float* premise    = (const float*)d_in[0];
  const float* hypothesis = (const float*)d_in[1];
  const float* aW1        = (const float*)d_in[2];
  const float* conv1_w    = (const float*)d_in[3];
  const float* conv1_b    = (const float*)d_in[4];
  const float* aW2        = (const float*)d_in[5];
  const float* conv2_w    = (const float*)d_in[6];
  const float* conv2_b    = (const float*)d_in[7];
  const float* out_w      = (const float*)d_in[8];
  const float* out_b      = (const float*)d_in[9];
  float* out = (float*)d_out;

  char* ws = (char*)d_ws;
  size_t off = 0;
  auto alloc = [&](size_t bytes) {
    void* p = ws + off;
    off += (bytes + 255) & ~(size_t)255;
    return p;
  };
  f16*   wTT1  = (f16*)alloc((size_t)14 * D0 * H * 2);
  f16*   wTT2  = (f16*)alloc((size_t)14 * H * H * 2);
  f16*   aWT1  = (f16*)alloc((size_t)D0 * 64 * 2);
  f16*   aWT2  = (f16*)alloc((size_t)H * 64 * 2);
  f16*   Xh    = (f16*)alloc((size_t)B * S * D0 * 2);
  f16*   Yh    = (f16*)alloc((size_t)B * S * D0 * 2);
  f16*   x1ah  = (f16*)alloc((size_t)B * S * D0 * 2);   // layer2 output aliases prefix
  f16*   x2ah  = (f16*)alloc((size_t)B * S * D0 * 2);
  f16*   attAh = (f16*)alloc((size_t)B * S * S * 2);    // reused layer1+2
  f16*   attTh = (f16*)alloc((size_t)B * S * S * 2);
  f16*   LI1h  = (f16*)alloc((size_t)B * S * H * 2);
  f16*   RI1h  = (f16*)alloc((size_t)B * S * H * 2);
  float* lcT   = (float*)alloc((size_t)B * T70 * H * 4);  // reused layer2
  float* rcT   = (float*)alloc((size_t)B * T70 * H * 4);
  f16*   lcTh  = (f16*)alloc((size_t)B * T70 * H * 2);
  f16*   rcTh  = (f16*)alloc((size_t)B * T70 * H * 2);
  float* LO0   = (float*)alloc((size_t)B * D0 * 4);
  float* RO0   = (float*)alloc((size_t)B * D0 * 4);
  float* LO1   = (float*)alloc((size_t)B * H * 4);
  float* RO1   = (float*)alloc((size_t)B * H * 4);
  float* LO2   = (float*)alloc((size_t)B * H * 4);
  float* RO2   = (float*)alloc((size_t)B * H * 4);
  float* la    = (float*)alloc((size_t)B * T70 * 4);
  float* ra    = (float*)alloc((size_t)B * T70 * 4);
  // total ~97 MB

  const int n4 = B * S * D0 / 4;
  // 0. converts + weight transposes
  k_cvt<<<(n4 + 255) / 256, 256, 0, stream>>>(premise, Xh, n4);
  k_cvt<<<(n4 + 255) / 256, 256, 0, stream>>>(hypothesis, Yh, n4);
  k_trw<<<dim3(D0 / 64, H / 64, 14), 256, 0, stream>>>(conv1_w, wTT1, D0, 14 * D0);
  k_trw<<<dim3(H / 64,  H / 64, 14), 256, 0, stream>>>(conv2_w, wTT2, H, 14 * H);
  k_trw_aw<<<D0 / 64, 256, 0, stream>>>(aW1, aWT1, D0);
  k_trw_aw<<<H  / 64, 256, 0, stream>>>(aW2, aWT2, H);
  // 1. LO0/RO0 (fp32 exact)
  k_mean<float><<<(B * D0 + 255) / 256, 256, 0, stream>>>(premise,    LO0, S, D0, 1.f / S);
  k_mean<float><<<(B * D0 + 255) / 256, 256, 0, stream>>>(hypothesis, RO0, S, D0, 1.f / S);
  // 2. att1 (MFMA) -> att + att^T fp16; xa1 (MFMA) -> x1ah/x2ah
  k_att<S, 64, D0, true, false><<<B, 256, 0, stream>>>(Xh, Yh, attAh, attTh, nullptr, nullptr);
  k_xa<<<dim3(D0 / 128, B), 256, 0, stream>>>(attAh, attTh, aWT1, x1ah, x2ah, D0);
  // 3. conv1 (z-fused MFMA) -> lcT/rcT fp32 + lcTh/rcTh fp16
  k_conv<D0><<<560, 256, 0, stream>>>(Xh, Yh, x1ah, x2ah, wTT1, conv1_b, lcT, rcT, lcTh, rcTh);
  // 4. att2 (MFMA, W=70 pad 96) -> row/col sums
  k_att<T70, 96, H, false, true><<<B, 256, 0, stream>>>(lcTh, rcTh, nullptr, nullptr, la, ra);
  // 5. LO1/RO1 (fp32 inputs)
  k_mean<float><<<(B * H + 255) / 256, 256, 0, stream>>>(lcT, LO1, T70, H, 1.f / T70);
  k_mean<float><<<(B * H + 255) / 256, 256, 0, stream>>>(rcT, RO1, T70, H, 1.f / T70);
  // 6. w_pool -> LI1h/RI1h fp16
  k_wpool<<<(B * S * H + 255) / 256, 256, 0, stream>>>(lcT, la, LI1h);
  k_wpool<<<(B * S * H + 255) / 256, 256, 0, stream>>>(rcT, ra, RI1h);
  // 7. layer-2 attention + xa (x1ah/x2ah reused as layer-2 buffers)
  k_att<S, 64, H, true, false><<<B, 256, 0, stream>>>(LI1h, RI1h, attAh, attTh, nullptr, nullptr);
  k_xa<<<dim3(H / 128, B), 256, 0, stream>>>(attAh, attTh, aWT2, x1ah, x2ah, H);
  // 8. conv2 (z-fused)
  k_conv<H><<<560, 256, 0, stream>>>(LI1h, RI1h, x1ah, x2ah, wTT2, conv2_b, lcT, rcT, lcTh, rcTh);
  // 9. LO2/RO2
  k_mean<float><<<(B * H + 255) / 256, 256, 0, stream>>>(lcT, LO2, T70, H, 1.f / T70);
  k_mean<float><<<(B * H + 255) / 256, 256, 0, stream>>>(rcT, RO2, T70, H, 1.f / T70);
  // 10. final
  k_final<<<B, 256, 0, stream>>>(LO0, RO0, LO1, RO1, LO2, RO2, out_w, out_b, out);
}

// Round 4
// 335.567 us; speedup vs baseline: 15.8308x; 1.3568x over previous
//
#include <hip/hip_runtime.h>
#include <math.h>

typedef _Float16 f16;
typedef _Float16 half8 __attribute__((ext_vector_type(8)));
typedef _Float16 half4 __attribute__((ext_vector_type(4)));
typedef float floatx4 __attribute__((ext_vector_type(4)));

constexpr int B   = 128;
constexpr int S   = 64;
constexpr int D0  = 768;
constexpr int H   = 256;
constexpr int KW  = 7;
constexpr int NC  = 3;
constexpr int T70 = S + KW - 1;  // 70
constexpr float EPSF = 1e-12f;

// ---------- fused fp32->fp16 convert + mean over t: in[B,S,D] -> outh fp16, mean[B,D] ----------
__global__ __launch_bounds__(256) void k_cvtmean(const float* __restrict__ in,
                                                 f16* __restrict__ outh,
                                                 float* __restrict__ mean) {
  constexpr int D4 = D0 / 4;
  const int idx = blockIdx.x * 256 + threadIdx.x;   // grid = B*D4/256 = 96 exact
  const int b = idx / D4, f4 = idx % D4;
  const float4* __restrict__ src = reinterpret_cast<const float4*>(in) + (size_t)b * S * D4 + f4;
  half4* __restrict__ dst = reinterpret_cast<half4*>(outh) + (size_t)b * S * D4 + f4;
  float4 acc = {0.f, 0.f, 0.f, 0.f};
  for (int t = 0; t < S; ++t) {
    float4 v = src[(size_t)t * D4];
    acc.x += v.x; acc.y += v.y; acc.z += v.z; acc.w += v.w;
    half4 o = {(f16)v.x, (f16)v.y, (f16)v.z, (f16)v.w};
    dst[(size_t)t * D4] = o;
  }
  const float inv = 1.f / S;
  mean[(size_t)b * D0 + f4 * 4 + 0] = acc.x * inv;
  mean[(size_t)b * D0 + f4 * 4 + 1] = acc.y * inv;
  mean[(size_t)b * D0 + f4 * 4 + 2] = acc.z * inv;
  mean[(size_t)b * D0 + f4 * 4 + 3] = acc.w * inv;
}

// ---------- conv weight transpose: cw[d,7,2,H] -> wTT[h][(k*2+c)*d+dd] fp16 ----------
__global__ __launch_bounds__(256) void k_trw(const float* __restrict__ cw,
                                             f16* __restrict__ wTT, int DPC, int Ktot) {
  __shared__ f16 tile[64][65];
  const int kc = blockIdx.z, k = kc >> 1, c = kc & 1;
  const int dd0 = blockIdx.x * 64, h0 = blockIdx.y * 64;
  const int tx = threadIdx.x & 63, ty = threadIdx.x >> 6;
#pragma unroll
  for (int i = 0; i < 64; i += 4) {
    int dd = dd0 + i + ty;
    tile[i + ty][tx] = (f16)cw[(size_t)((dd * KW + k) * 2 + c) * H + h0 + tx];
  }
  __syncthreads();
#pragma unroll
  for (int i = 0; i < 64; i += 4) {
    int h = h0 + i + ty;
    wTT[(size_t)h * Ktot + (size_t)kc * DPC + dd0 + tx] = tile[tx][i + ty];
  }
}

// ---------- aW[S=64][D] fp32 -> aWT[D][64] fp16 ----------
__global__ __launch_bounds__(256) void k_trw_aw(const float* __restrict__ aW,
                                                f16* __restrict__ aWT, int D) {
  __shared__ f16 tile[64][65];
  const int d0 = blockIdx.x * 64;
  const int tx = threadIdx.x & 63, ty = threadIdx.x >> 6;
#pragma unroll
  for (int i = 0; i < 64; i += 4) {
    int s = i + ty;
    tile[s][tx] = (f16)aW[(size_t)s * D + d0 + tx];
  }
  __syncthreads();
#pragma unroll
  for (int i = 0; i < 64; i += 4) {
    int d = i + ty;
    aWT[(size_t)(d0 + d) * 64 + tx] = tile[tx][d];
  }
}

// ---------- mean over axis 1 of [B,T,F] -> [B,F] fp32 ----------
template<typename T>
__global__ __launch_bounds__(256) void k_mean(const T* __restrict__ x,
                                              float* __restrict__ out,
                                              int Tr, int F, float inv) {
  int idx = blockIdx.x * 256 + threadIdx.x;
  if (idx >= B * F) return;
  int b = idx / F, f = idx % F;
  const T* p = x + (size_t)b * Tr * F + f;
  float s = 0.f;
  for (int t = 0; t < Tr; ++t) s += (float)p[(size_t)t * F];
  out[idx] = s * inv;
}

// ---------- MFMA attention: att[i][j] = 1/(1+sqrt(max(n1+n2-2*x1_i.x2_j,0)+eps)) ----------
template<int W, int WP, int D, bool STORE, bool SUMS>
__global__ __launch_bounds__(256) void k_att(const f16* __restrict__ X1,
                                             const f16* __restrict__ X2,
                                             f16* __restrict__ attA,
                                             f16* __restrict__ attT,
                                             float* __restrict__ la,
                                             float* __restrict__ ra) {
  constexpr int FR = WP / 32;
  __shared__ half8 As[WP * 4];
  __shared__ half8 Bs[WP * 4];
  __shared__ float n1s[WP], n2s[WP];
  __shared__ float att_s[SUMS ? WP * (WP + 1) : 1];

  const int b = blockIdx.x, tid = threadIdx.x;
  const int lane = tid & 63, wave = tid >> 6;
  const int wr = wave >> 1, wc = wave & 1;
  const int l15 = lane & 15, g = lane >> 4;
  const f16* __restrict__ x1 = X1 + (size_t)b * W * D;
  const f16* __restrict__ x2 = X2 + (size_t)b * W * D;

  floatx4 acc[FR][FR];
#pragma unroll
  for (int i = 0; i < FR; ++i)
#pragma unroll
    for (int j = 0; j < FR; ++j) acc[i][j] = (floatx4)0.f;
  float na1 = 0.f, na2 = 0.f;

  for (int k0 = 0; k0 < D; k0 += 32) {
    __syncthreads();
    for (int u = tid; u < WP * 4; u += 256) {
      const int r = u >> 2, c = u & 3;
      half8 v1 = (half8)(f16)0.f, v2 = (half8)(f16)0.f;
      if (r < W) {
        v1 = *reinterpret_cast<const half8*>(x1 + (size_t)r * D + k0 + c * 8);
        v2 = *reinterpret_cast<const half8*>(x2 + (size_t)r * D + k0 + c * 8);
      }
      const int p = r * 4 + (c ^ ((r >> 1) & 3));
      As[p] = v1;
      Bs[p] = v2;
    }
    __syncthreads();
    half8 af[FR], bf[FR];
#pragma unroll
    for (int fi = 0; fi < FR; ++fi) {
      const int row = wr * 16 * FR + fi * 16 + l15;
      af[fi] = As[row * 4 + (g ^ ((row >> 1) & 3))];
    }
#pragma unroll
    for (int fj = 0; fj < FR; ++fj) {
      const int row = wc * 16 * FR + fj * 16 + l15;
      bf[fj] = Bs[row * 4 + (g ^ ((row >> 1) & 3))];
    }
#pragma unroll
    for (int fi = 0; fi < FR; ++fi)
#pragma unroll
      for (int fj = 0; fj < FR; ++fj)
        acc[fi][fj] = __builtin_amdgcn_mfma_f32_16x16x32_f16(af[fi], bf[fj], acc[fi][fj], 0, 0, 0);
    if (tid < WP) {
      const int r = tid;
#pragma unroll
      for (int c = 0; c < 4; ++c) {
        half8 v = As[r * 4 + (c ^ ((r >> 1) & 3))];
#pragma unroll
        for (int e = 0; e < 8; ++e) { float f = (float)v[e]; na1 = fmaf(f, f, na1); }
      }
    } else if (tid >= 128 && tid < 128 + WP) {
      const int r = tid - 128;
#pragma unroll
      for (int c = 0; c < 4; ++c) {
        half8 v = Bs[r * 4 + (c ^ ((r >> 1) & 3))];
#pragma unroll
        for (int e = 0; e < 8; ++e) { float f = (float)v[e]; na2 = fmaf(f, f, na2); }
      }
    }
  }
  if (tid < WP) n1s[tid] = na1;
  if (tid >= 128 && tid < 128 + WP) n2s[tid - 128] = na2;
  __syncthreads();

#pragma unroll
  for (int fi = 0; fi < FR; ++fi)
#pragma unroll
    for (int fj = 0; fj < FR; ++fj)
#pragma unroll
      for (int r = 0; r < 4; ++r) {
        const int i = wr * 16 * FR + fi * 16 + g * 4 + r;
        const int j = wc * 16 * FR + fj * 16 + l15;
        if (i < W && j < W) {
          float sq = fmaxf(n1s[i] + n2s[j] - 2.f * acc[fi][fj][r], 0.f);
          const float v = 1.f / (1.f + sqrtf(sq + EPSF));
          if (STORE) {
            attA[((size_t)b * W + i) * W + j] = (f16)v;
            attT[((size_t)b * W + j) * W + i] = (f16)v;
          }
          if (SUMS) att_s[i * (WP + 1) + j] = v;
        }
      }
  if (SUMS) {
    __syncthreads();
    if (tid < W) {
      float sum = 0.f;
      for (int j = 0; j < W; ++j) sum += att_s[tid * (WP + 1) + j];
      la[b * W + tid] = sum;
    }
    if (tid >= 128 && tid < 128 + W) {
      const int j = tid - 128;
      float sum = 0.f;
      for (int i = 0; i < W; ++i) sum += att_s[i * (WP + 1) + j];
      ra[b * W + j] = sum;
    }
  }
}

// ---------- MFMA xa: x1a[i][d]=sum_j attA[i][j]*aWT[d][j]; x2a from attT ----------
__global__ __launch_bounds__(256) void k_xa(const f16* __restrict__ attA,
                                            const f16* __restrict__ attT,
                                            const f16* __restrict__ aWT,
                                            f16* __restrict__ x1a,
                                            f16* __restrict__ x2a, int D) {
  __shared__ half8 As[64 * 8];
  __shared__ half8 Ts[64 * 8];
  __shared__ half8 Bs[128 * 8];
  const int b = blockIdx.y, d0 = blockIdx.x * 128;
  const int tid = threadIdx.x;
  const int lane = tid & 63, wave = tid >> 6;
  const int wr = wave >> 1, wc = wave & 1;
  const int l15 = lane & 15, g = lane >> 4;
  const int r0 = tid >> 3, c8 = tid & 7;

#pragma unroll
  for (int p = 0; p < 2; ++p) {
    const int r = r0 + p * 32;
    const int sw = r * 8 + (c8 ^ (r & 7));
    As[sw] = *reinterpret_cast<const half8*>(attA + ((size_t)b * 64 + r) * 64 + c8 * 8);
    Ts[sw] = *reinterpret_cast<const half8*>(attT + ((size_t)b * 64 + r) * 64 + c8 * 8);
  }
#pragma unroll
  for (int p = 0; p < 4; ++p) {
    const int r = r0 + p * 32;
    Bs[r * 8 + (c8 ^ (r & 7))] =
        *reinterpret_cast<const half8*>(aWT + (size_t)(d0 + r) * 64 + c8 * 8);
  }
  __syncthreads();

  floatx4 acc1[2][4], acc2[2][4];
#pragma unroll
  for (int i = 0; i < 2; ++i)
#pragma unroll
    for (int j = 0; j < 4; ++j) { acc1[i][j] = (floatx4)0.f; acc2[i][j] = (floatx4)0.f; }

#pragma unroll
  for (int ks = 0; ks < 2; ++ks) {
    half8 a1[2], a2[2], bf[4];
#pragma unroll
    for (int i = 0; i < 2; ++i) {
      const int row = wr * 32 + i * 16 + l15;
      const int ch = ks * 4 + g;
      a1[i] = As[row * 8 + (ch ^ (row & 7))];
      a2[i] = Ts[row * 8 + (ch ^ (row & 7))];
    }
#pragma unroll
    for (int j = 0; j < 4; ++j) {
      const int row = wc * 64 + j * 16 + l15;
      const int ch = ks * 4 + g;
      bf[j] = Bs[row * 8 + (ch ^ (row & 7))];
    }
#pragma unroll
    for (int i = 0; i < 2; ++i)
#pragma unroll
      for (int j = 0; j < 4; ++j) {
        acc1[i][j] = __builtin_amdgcn_mfma_f32_16x16x32_f16(a1[i], bf[j], acc1[i][j], 0, 0, 0);
        acc2[i][j] = __builtin_amdgcn_mfma_f32_16x16x32_f16(a2[i], bf[j], acc2[i][j], 0, 0, 0);
      }
  }
#pragma unroll
  for (int i = 0; i < 2; ++i)
#pragma unroll
    for (int j = 0; j < 4; ++j)
#pragma unroll
      for (int r = 0; r < 4; ++r) {
        const int m = wr * 32 + i * 16 + g * 4 + r;
        const int d = d0 + wc * 64 + j * 16 + l15;
        x1a[((size_t)b * S + m) * D + d] = (f16)acc1[i][j][r];
        x2a[((size_t)b * S + m) * D + d] = (f16)acc2[i][j][r];
      }
}

// ---------- conv as im2col MFMA GEMM: A-window staging + depth-2 B pipeline ----------
// A-window: W[c][j], j in [0,70): virtual row u = m0-6+j; value = src[bn(u)*64 + u%70]
// if u>=0 && u%70<64 else 0 (function of u alone; (m,k) -> j = r+k).
template<int DPC>
__global__ __launch_bounds__(256) void k_conv(const f16* __restrict__ X0,
                                              const f16* __restrict__ X1v,
                                              const f16* __restrict__ XA0,
                                              const f16* __restrict__ XA1,
                                              const f16* __restrict__ wTT,
                                              const float* __restrict__ bias,
                                              f16* __restrict__ O16_0,
                                              f16* __restrict__ O16_1) {
  constexpr int NDQ = DPC / 64;
  constexpr int NSTEP = NDQ * 14;      // ks: dq = ks/14, kc = ks%14
  constexpr int KTOT = 14 * DPC;
  __shared__ half8 Wl[2][70 * 8];      // A-window, single-buffered per dq
  __shared__ half8 B8[2][128 * 8];     // B tiles, double-buffered

  const int tid = threadIdx.x;
  const int bid = blockIdx.x;
  const int xcd = bid & 7, slot = bid >> 3;
  const int n0 = (xcd >> 2) * 128;
  const int w = slot * 4 + (xcd & 3);
  const int z = w & 1, mblk = w >> 1;
  const int m0 = mblk * 64;
  const f16* __restrict__ Xs  = z ? X1v : X0;
  const f16* __restrict__ XAs = z ? XA1 : XA0;
  f16* __restrict__ Out16 = z ? O16_1 : O16_0;

  const int lane = tid & 63, wave = tid >> 6;
  const int wr = wave >> 1, wc = wave & 1;
  const int l15 = lane & 15, g = lane >> 4;
  const int r0 = tid >> 3, c8 = tid & 7;

  // A-window source addressing (rows j = r0, r0+32, 64+r0 if r0<6)
  int jr[3] = {r0, r0 + 32, 64 + r0};
  size_t aoff[3];
  bool aval[3];
#pragma unroll
  for (int p = 0; p < 3; ++p) {
    const int u = m0 - 6 + jr[p];
    const int uc = u < 0 ? 0 : u;
    const int bn = uc / T70;
    const int tl = uc - bn * T70;
    aval[p] = (u >= 0) && (tl < S);
    aoff[p] = (size_t)(bn * S + tl) * DPC + (size_t)c8 * 8;
  }
  const f16* bpv[4];
#pragma unroll
  for (int p = 0; p < 4; ++p)
    bpv[p] = wTT + (size_t)(n0 + r0 + p * 32) * KTOT + (size_t)c8 * 8;

  floatx4 acc[2][4];
#pragma unroll
  for (int i = 0; i < 2; ++i)
#pragma unroll
    for (int j = 0; j < 4; ++j) acc[i][j] = (floatx4)0.f;

  half8 rA[2][3];
  auto aLoad = [&](int dq) {
    const size_t co = (size_t)dq * 64;
#pragma unroll
    for (int c = 0; c < 2; ++c) {
      const f16* __restrict__ src = c ? XAs : Xs;
#pragma unroll
      for (int p = 0; p < 2; ++p)
        rA[c][p] = aval[p] ? *reinterpret_cast<const half8*>(src + aoff[p] + co)
                           : (half8)(f16)0.f;
      if (r0 < 6)
        rA[c][2] = aval[2] ? *reinterpret_cast<const half8*>(src + aoff[2] + co)
                           : (half8)(f16)0.f;
    }
  };
  auto aWrite = [&]() {
#pragma unroll
    for (int c = 0; c < 2; ++c) {
#pragma unroll
      for (int p = 0; p < 2; ++p) {
        const int j = jr[p];
        Wl[c][j * 8 + (c8 ^ (j & 7))] = rA[c][p];
      }
      if (r0 < 6) {
        const int j = jr[2];
        Wl[c][j * 8 + (c8 ^ (j & 7))] = rA[c][2];
      }
    }
  };
  auto bLoad = [&](half8* rB, int ks) {
    const int dq = ks / 14, kc = ks % 14;
    const size_t o = (size_t)kc * DPC + (size_t)dq * 64;
#pragma unroll
    for (int p = 0; p < 4; ++p)
      rB[p] = *reinterpret_cast<const half8*>(bpv[p] + o);
  };
  auto bWrite = [&](const half8* rB, int buf) {
#pragma unroll
    for (int p = 0; p < 4; ++p) {
      const int r = r0 + p * 32;
      B8[buf][r * 8 + (c8 ^ (r & 7))] = rB[p];
    }
  };
  auto compute = [&](int ks) {
    const int kc = ks % 14, k = kc >> 1, c = kc & 1;
    const int buf = ks & 1;
    half8 af[2][2], bf[4][2];
#pragma unroll
    for (int i = 0; i < 2; ++i) {
      const int j = wr * 32 + i * 16 + l15 + k;
#pragma unroll
      for (int sub = 0; sub < 2; ++sub)
        af[i][sub] = Wl[c][j * 8 + ((sub * 4 + g) ^ (j & 7))];
    }
#pragma unroll
    for (int jx = 0; jx < 4; ++jx) {
      const int row = wc * 64 + jx * 16 + l15;
#pragma unroll
      for (int sub = 0; sub < 2; ++sub)
        bf[jx][sub] = B8[buf][row * 8 + ((sub * 4 + g) ^ (row & 7))];
    }
#pragma unroll
    for (int sub = 0; sub < 2; ++sub)
#pragma unroll
      for (int i = 0; i < 2; ++i)
#pragma unroll
        for (int jx = 0; jx < 4; ++jx)
          acc[i][jx] = __builtin_amdgcn_mfma_f32_16x16x32_f16(af[i][sub], bf[jx][sub], acc[i][jx], 0, 0, 0);
  };

  half8 rBa[4], rBb[4];
  // prologue: A(dq0) + B tile0 in LDS; B tile1 in regs
  aLoad(0);
  bLoad(rBa, 0);
  aWrite();
  bWrite(rBa, 0);
  bLoad(rBa, 1);
  __syncthreads();

  auto body = [&](int ks, half8* rCur, half8* rNxt) {
    if (ks + 2 < NSTEP) bLoad(rNxt, ks + 2);                 // 2-ahead B prefetch
    if ((ks % 14) == 12 && (ks / 14 + 1) < NDQ) aLoad(ks / 14 + 1);
    compute(ks);
    if (ks + 1 < NSTEP) {
      if (((ks + 1) % 14) == 0) { __syncthreads(); aWrite(); }  // new dq window
      bWrite(rCur, (ks + 1) & 1);
    }
    __syncthreads();
  };
  for (int ks2 = 0; ks2 < NSTEP; ks2 += 2) {
    body(ks2, rBa, rBb);
    body(ks2 + 1, rBb, rBa);
  }

  // epilogue: fp16 only
#pragma unroll
  for (int i = 0; i < 2; ++i) {
    const int mr = m0 + wr * 32 + i * 16 + g * 4;
#pragma unroll
    for (int j = 0; j < 4; ++j) {
      const int h = n0 + wc * 64 + j * 16 + l15;
      const float bv = bias[h];
#pragma unroll
      for (int r = 0; r < 4; ++r)
        Out16[(size_t)(mr + r) * H + h] = (f16)tanhf(acc[i][j][r] + bv);
    }
  }
}

// ---------- fused all-pool mean + attention-weighted window pool ----------
// grid (B, 2). Reads lcTh/rcTh fp16 once; LO[b,h]=mean_t; LI[b,s,h]=sum_j lc[s+j]*a[s+j]
__global__ __launch_bounds__(256) void k_powl(const f16* __restrict__ lcTh,
                                              const f16* __restrict__ rcTh,
                                              const float* __restrict__ la,
                                              const float* __restrict__ ra,
                                              float* __restrict__ LO1,
                                              float* __restrict__ RO1,
                                              f16* __restrict__ LI1h,
                                              f16* __restrict__ RI1h) {
  const int b = blockIdx.x, side = blockIdx.y;
  const f16* __restrict__ xc = (side ? rcTh : lcTh) + (size_t)b * T70 * H;
  const float* __restrict__ av = (side ? ra : la) + (size_t)b * T70;
  float* __restrict__ LO = side ? RO1 : LO1;
  f16* __restrict__ LI = (side ? RI1h : LI1h) + (size_t)b * S * H;
  __shared__ float a_s[T70];
  __shared__ f16 wv[T70][H];
  const int h = threadIdx.x;
  if (h < T70) a_s[h] = av[h];
  __syncthreads();
  float sum = 0.f;
  for (int t = 0; t < T70; ++t) {
    const float v = (float)xc[(size_t)t * H + h];
    sum += v;
    wv[t][h] = (f16)(v * a_s[t]);
  }
  LO[(size_t)b * H + h] = sum * (1.f / T70);
  __syncthreads();
  for (int s = 0; s < S; ++s) {
    float acc = 0.f;
#pragma unroll
    for (int j = 0; j < KW; ++j) acc += (float)wv[s + j][h];
    LI[(size_t)s * H + h] = (f16)acc;
  }
}

// ---------- cosine sims + final tiny GEMM ----------
__global__ __launch_bounds__(256) void k_final(const float* __restrict__ LO0,
                                               const float* __restrict__ RO0,
                                               const float* __restrict__ LO1,
                                               const float* __restrict__ RO1,
                                               const float* __restrict__ LO2,
                                               const float* __restrict__ RO2,
                                               const float* __restrict__ out_w,
                                               const float* __restrict__ out_b,
                                               float* __restrict__ out) {
  const int b = blockIdx.x;
  const int tid = threadIdx.x;
  __shared__ float red[3][4];
  __shared__ float sims[3];
  const float* Ls[3] = {LO0 + (size_t)b * D0, LO1 + (size_t)b * H, LO2 + (size_t)b * H};
  const float* Rs[3] = {RO0 + (size_t)b * D0, RO1 + (size_t)b * H, RO2 + (size_t)b * H};
  const int dims[3] = {D0, H, H};
#pragma unroll
  for (int p = 0; p < 3; ++p) {
    float dot = 0.f, q1 = 0.f, q2 = 0.f;
    for (int i = tid; i < dims[p]; i += 256) {
      const float v1 = Ls[p][i], v2 = Rs[p][i];
      dot = fmaf(v1, v2, dot);
      q1  = fmaf(v1, v1, q1);
      q2  = fmaf(v2, v2, q2);
    }
#pragma unroll
    for (int off = 32; off > 0; off >>= 1) {
      dot += __shfl_down(dot, off);
      q1  += __shfl_down(q1, off);
      q2  += __shfl_down(q2, off);
    }
    if ((tid & 63) == 0) { red[0][tid >> 6] = dot; red[1][tid >> 6] = q1; red[2][tid >> 6] = q2; }
    __syncthreads();
    if (tid == 0) {
      float d = red[0][0] + red[0][1] + red[0][2] + red[0][3];
      float a = red[1][0] + red[1][1] + red[1][2] + red[1][3];
      float c = red[2][0] + red[2][1] + red[2][2] + red[2][3];
      sims[p] = d / (sqrtf(a) * sqrtf(c) + EPSF);
    }
    __syncthreads();
  }
  if (tid < NC) {
    float v = out_b[tid];
#pragma unroll
    for (int k = 0; k < 3; ++k) v = fmaf(sims[k], out_w[k * NC + tid], v);
    out[b * NC + tid] = v;
  }
}

extern "C" void kernel_launch(void* const* d_in, const int* in_sizes, int n_in,
                              void* d_out, int out_size, void* d_ws, size_t ws_size,
                              hipStream_t stream) {
  const float* premise    = (const float*)d_in[0];
  const float* hypothesis = (const float*)d_in[1];
  const float* aW1        = (const float*)d_in[2];
  const float* conv1_w    = (const float*)d_in[3];
  const float* conv1_b    = (const float*)d_in[4];
  const float* aW2        = (const float*)d_in[5];
  const float* conv2_w    = (const float*)d_in[6];
  const float* conv2_b    = (const float*)d_in[7];
  const float* out_w      = (const float*)d_in[8];
  const float* out_b      = (const float*)d_in[9];
  float* out = (float*)d_out;

  char* ws = (char*)d_ws;
  size_t off = 0;
  auto alloc = [&](size_t bytes) {
    void* p = ws + off;
    off += (bytes + 255) & ~(size_t)255;
    return p;
  };
  f16*   wTT1  = (f16*)alloc((size_t)14 * D0 * H * 2);
  f16*   wTT2  = (f16*)alloc((size_t)14 * H * H * 2);
  f16*   aWT1  = (f16*)alloc((size_t)D0 * 64 * 2);
  f16*   aWT2  = (f16*)alloc((size_t)H * 64 * 2);
  f16*   Xh    = (f16*)alloc((size_t)B * S * D0 * 2);
  f16*   Yh    = (f16*)alloc((size_t)B * S * D0 * 2);
  f16*   x1ah  = (f16*)alloc((size_t)B * S * D0 * 2);   // layer2 output aliases prefix
  f16*   x2ah  = (f16*)alloc((size_t)B * S * D0 * 2);
  f16*   attAh = (f16*)alloc((size_t)B * S * S * 2);
  f16*   attTh = (f16*)alloc((size_t)B * S * S * 2);
  f16*   LI1h  = (f16*)alloc((size_t)B * S * H * 2);
  f16*   RI1h  = (f16*)alloc((size_t)B * S * H * 2);
  f16*   lcTh  = (f16*)alloc((size_t)B * T70 * H * 2);  // reused layer2
  f16*   rcTh  = (f16*)alloc((size_t)B * T70 * H * 2);
  float* LO0   = (float*)alloc((size_t)B * D0 * 4);
  float* RO0   = (float*)alloc((size_t)B * D0 * 4);
  float* LO1   = (float*)alloc((size_t)B * H * 4);
  float* RO1   = (float*)alloc((size_t)B * H * 4);
  float* LO2   = (float*)alloc((size_t)B * H * 4);
  float* RO2   = (float*)alloc((size_t)B * H * 4);
  float* la    = (float*)alloc((size_t)B * T70 * 4);
  float* ra    = (float*)alloc((size_t)B * T70 * 4);

  // 0. fused convert+mean, weight transposes
  k_cvtmean<<<B * (D0 / 4) / 256, 256, 0, stream>>>(premise,    Xh, LO0);
  k_cvtmean<<<B * (D0 / 4) / 256, 256, 0, stream>>>(hypothesis, Yh, RO0);
  k_trw<<<dim3(D0 / 64, H / 64, 14), 256, 0, stream>>>(conv1_w, wTT1, D0, 14 * D0);
  k_trw<<<dim3(H / 64,  H / 64, 14), 256, 0, stream>>>(conv2_w, wTT2, H, 14 * H);
  k_trw_aw<<<D0 / 64, 256, 0, stream>>>(aW1, aWT1, D0);
  k_trw_aw<<<H  / 64, 256, 0, stream>>>(aW2, aWT2, H);
  // 1. att1 + xa1
  k_att<S, 64, D0, true, false><<<B, 256, 0, stream>>>(Xh, Yh, attAh, attTh, nullptr, nullptr);
  k_xa<<<dim3(D0 / 128, B), 256, 0, stream>>>(attAh, attTh, aWT1, x1ah, x2ah, D0);
  // 2. conv1 (A-window + depth-2 pipeline) -> lcTh/rcTh fp16
  k_conv<D0><<<560, 256, 0, stream>>>(Xh, Yh, x1ah, x2ah, wTT1, conv1_b, lcTh, rcTh);
  // 3. att2 sums
  k_att<T70, 96, H, false, true><<<B, 256, 0, stream>>>(lcTh, rcTh, nullptr, nullptr, la, ra);
  // 4. fused mean + wpool
  k_powl<<<dim3(B, 2), 256, 0, stream>>>(lcTh, rcTh, la, ra, LO1, RO1, LI1h, RI1h);
  // 5. layer-2 att + xa
  k_att<S, 64, H, true, false><<<B, 256, 0, stream>>>(LI1h, RI1h, attAh, attTh, nullptr, nullptr);
  k_xa<<<dim3(H / 128, B), 256, 0, stream>>>(attAh, attTh, aWT2, x1ah, x2ah, H);
  // 6. conv2 -> reuse lcTh/rcTh
  k_conv<H><<<560, 256, 0, stream>>>(LI1h, RI1h, x1ah, x2ah, wTT2, conv2_b, lcTh, rcTh);
  // 7. LO2/RO2
  k_mean<f16><<<(B * H + 255) / 256, 256, 0, stream>>>(lcTh, LO2, T70, H, 1.f / T70);
  k_mean<f16><<<(B * H + 255) / 256, 256, 0, stream>>>(rcTh, RO2, T70, H, 1.f / T70);
  // 8. final
  k_final<<<B, 256, 0, stream>>>(LO0, RO0, LO1, RO1, LO2, RO2, out_w, out_b, out);
}

// Round 5
// 334.442 us; speedup vs baseline: 15.8840x; 1.0034x over previous
//
#include <hip/hip_runtime.h>
#include <math.h>

typedef _Float16 f16;
typedef _Float16 half8 __attribute__((ext_vector_type(8)));
typedef _Float16 half4 __attribute__((ext_vector_type(4)));
typedef float floatx4 __attribute__((ext_vector_type(4)));

constexpr int B   = 128;
constexpr int S   = 64;
constexpr int D0  = 768;
constexpr int H   = 256;
constexpr int KW  = 7;
constexpr int NC  = 3;
constexpr int T70 = S + KW - 1;  // 70
constexpr float EPSF = 1e-12f;

// ---------- fused fp32->fp16 convert + mean over t, both sides ----------
__global__ __launch_bounds__(256) void k_cvtmean(const float* __restrict__ in0,
                                                 const float* __restrict__ in1,
                                                 f16* __restrict__ oh0,
                                                 f16* __restrict__ oh1,
                                                 float* __restrict__ mn0,
                                                 float* __restrict__ mn1) {
  constexpr int D4 = D0 / 4;
  const int side = blockIdx.y;
  const float* __restrict__ in = side ? in1 : in0;
  f16* __restrict__ outh = side ? oh1 : oh0;
  float* __restrict__ mean = side ? mn1 : mn0;
  const int idx = blockIdx.x * 256 + threadIdx.x;   // grid.x = B*D4/256 = 96
  const int b = idx / D4, f4 = idx % D4;
  const float4* __restrict__ src = reinterpret_cast<const float4*>(in) + (size_t)b * S * D4 + f4;
  half4* __restrict__ dst = reinterpret_cast<half4*>(outh) + (size_t)b * S * D4 + f4;
  float4 acc = {0.f, 0.f, 0.f, 0.f};
  for (int t = 0; t < S; ++t) {
    float4 v = src[(size_t)t * D4];
    acc.x += v.x; acc.y += v.y; acc.z += v.z; acc.w += v.w;
    half4 o = {(f16)v.x, (f16)v.y, (f16)v.z, (f16)v.w};
    dst[(size_t)t * D4] = o;
  }
  const float inv = 1.f / S;
  mean[(size_t)b * D0 + f4 * 4 + 0] = acc.x * inv;
  mean[(size_t)b * D0 + f4 * 4 + 1] = acc.y * inv;
  mean[(size_t)b * D0 + f4 * 4 + 2] = acc.z * inv;
  mean[(size_t)b * D0 + f4 * 4 + 3] = acc.w * inv;
}

// ---------- conv weight transpose: cw[d,7,2,H] -> wTT[h][(k*2+c)*d+dd] fp16 ----------
__global__ __launch_bounds__(256) void k_trw(const float* __restrict__ cw,
                                             f16* __restrict__ wTT, int DPC, int Ktot) {
  __shared__ f16 tile[64][65];
  const int kc = blockIdx.z, k = kc >> 1, c = kc & 1;
  const int dd0 = blockIdx.x * 64, h0 = blockIdx.y * 64;
  const int tx = threadIdx.x & 63, ty = threadIdx.x >> 6;
#pragma unroll
  for (int i = 0; i < 64; i += 4) {
    int dd = dd0 + i + ty;
    tile[i + ty][tx] = (f16)cw[(size_t)((dd * KW + k) * 2 + c) * H + h0 + tx];
  }
  __syncthreads();
#pragma unroll
  for (int i = 0; i < 64; i += 4) {
    int h = h0 + i + ty;
    wTT[(size_t)h * Ktot + (size_t)kc * DPC + dd0 + tx] = tile[tx][i + ty];
  }
}

// ---------- aW[S=64][D] fp32 -> aWT[D][64] fp16 ----------
__global__ __launch_bounds__(256) void k_trw_aw(const float* __restrict__ aW,
                                                f16* __restrict__ aWT, int D) {
  __shared__ f16 tile[64][65];
  const int d0 = blockIdx.x * 64;
  const int tx = threadIdx.x & 63, ty = threadIdx.x >> 6;
#pragma unroll
  for (int i = 0; i < 64; i += 4) {
    int s = i + ty;
    tile[s][tx] = (f16)aW[(size_t)s * D + d0 + tx];
  }
  __syncthreads();
#pragma unroll
  for (int i = 0; i < 64; i += 4) {
    int d = i + ty;
    aWT[(size_t)(d0 + d) * 64 + tx] = tile[tx][d];
  }
}

// ---------- merged means over axis 1 of [B,70,H] fp16 -> [B,H] fp32, 2 sides ----------
__global__ __launch_bounds__(256) void k_mean2(const f16* __restrict__ xa,
                                               const f16* __restrict__ xb,
                                               float* __restrict__ oa,
                                               float* __restrict__ ob) {
  const int side = blockIdx.y;
  const f16* __restrict__ x = side ? xb : xa;
  float* __restrict__ o = side ? ob : oa;
  int idx = blockIdx.x * 256 + threadIdx.x;
  if (idx >= B * H) return;
  int b = idx / H, f = idx % H;
  const f16* p = x + (size_t)b * T70 * H + f;
  float s = 0.f;
  for (int t = 0; t < T70; ++t) s += (float)p[(size_t)t * H];
  o[idx] = s * (1.f / T70);
}

// ---------- MFMA attention (generic, used for att2 sums) ----------
template<int W, int WP, int D, bool STORE, bool SUMS>
__global__ __launch_bounds__(256) void k_att(const f16* __restrict__ X1,
                                             const f16* __restrict__ X2,
                                             f16* __restrict__ attA,
                                             f16* __restrict__ attT,
                                             float* __restrict__ la,
                                             float* __restrict__ ra) {
  constexpr int FR = WP / 32;
  __shared__ half8 As[WP * 4];
  __shared__ half8 Bs[WP * 4];
  __shared__ float n1s[WP], n2s[WP];
  __shared__ float att_s[SUMS ? WP * (WP + 1) : 1];

  const int b = blockIdx.x, tid = threadIdx.x;
  const int lane = tid & 63, wave = tid >> 6;
  const int wr = wave >> 1, wc = wave & 1;
  const int l15 = lane & 15, g = lane >> 4;
  const f16* __restrict__ x1 = X1 + (size_t)b * W * D;
  const f16* __restrict__ x2 = X2 + (size_t)b * W * D;

  floatx4 acc[FR][FR];
#pragma unroll
  for (int i = 0; i < FR; ++i)
#pragma unroll
    for (int j = 0; j < FR; ++j) acc[i][j] = (floatx4)0.f;
  float na1 = 0.f, na2 = 0.f;

  for (int k0 = 0; k0 < D; k0 += 32) {
    __syncthreads();
    for (int u = tid; u < WP * 4; u += 256) {
      const int r = u >> 2, c = u & 3;
      half8 v1 = (half8)(f16)0.f, v2 = (half8)(f16)0.f;
      if (r < W) {
        v1 = *reinterpret_cast<const half8*>(x1 + (size_t)r * D + k0 + c * 8);
        v2 = *reinterpret_cast<const half8*>(x2 + (size_t)r * D + k0 + c * 8);
      }
      const int p = r * 4 + (c ^ ((r >> 1) & 3));
      As[p] = v1;
      Bs[p] = v2;
    }
    __syncthreads();
    half8 af[FR], bf[FR];
#pragma unroll
    for (int fi = 0; fi < FR; ++fi) {
      const int row = wr * 16 * FR + fi * 16 + l15;
      af[fi] = As[row * 4 + (g ^ ((row >> 1) & 3))];
    }
#pragma unroll
    for (int fj = 0; fj < FR; ++fj) {
      const int row = wc * 16 * FR + fj * 16 + l15;
      bf[fj] = Bs[row * 4 + (g ^ ((row >> 1) & 3))];
    }
#pragma unroll
    for (int fi = 0; fi < FR; ++fi)
#pragma unroll
      for (int fj = 0; fj < FR; ++fj)
        acc[fi][fj] = __builtin_amdgcn_mfma_f32_16x16x32_f16(af[fi], bf[fj], acc[fi][fj], 0, 0, 0);
    if (tid < WP) {
      const int r = tid;
#pragma unroll
      for (int c = 0; c < 4; ++c) {
        half8 v = As[r * 4 + (c ^ ((r >> 1) & 3))];
#pragma unroll
        for (int e = 0; e < 8; ++e) { float f = (float)v[e]; na1 = fmaf(f, f, na1); }
      }
    } else if (tid >= 128 && tid < 128 + WP) {
      const int r = tid - 128;
#pragma unroll
      for (int c = 0; c < 4; ++c) {
        half8 v = Bs[r * 4 + (c ^ ((r >> 1) & 3))];
#pragma unroll
        for (int e = 0; e < 8; ++e) { float f = (float)v[e]; na2 = fmaf(f, f, na2); }
      }
    }
  }
  if (tid < WP) n1s[tid] = na1;
  if (tid >= 128 && tid < 128 + WP) n2s[tid - 128] = na2;
  __syncthreads();

#pragma unroll
  for (int fi = 0; fi < FR; ++fi)
#pragma unroll
    for (int fj = 0; fj < FR; ++fj)
#pragma unroll
      for (int r = 0; r < 4; ++r) {
        const int i = wr * 16 * FR + fi * 16 + g * 4 + r;
        const int j = wc * 16 * FR + fj * 16 + l15;
        if (i < W && j < W) {
          float sq = fmaxf(n1s[i] + n2s[j] - 2.f * acc[fi][fj][r], 0.f);
          const float v = 1.f / (1.f + sqrtf(sq + EPSF));
          if (STORE) {
            attA[((size_t)b * W + i) * W + j] = (f16)v;
            attT[((size_t)b * W + j) * W + i] = (f16)v;
          }
          if (SUMS) att_s[i * (WP + 1) + j] = v;
        }
      }
  if (SUMS) {
    __syncthreads();
    if (tid < W) {
      float sum = 0.f;
      for (int j = 0; j < W; ++j) sum += att_s[tid * (WP + 1) + j];
      la[b * W + tid] = sum;
    }
    if (tid >= 128 && tid < 128 + W) {
      const int j = tid - 128;
      float sum = 0.f;
      for (int i = 0; i < W; ++i) sum += att_s[i * (WP + 1) + j];
      ra[b * W + j] = sum;
    }
  }
}

// ---------- FUSED att + xa: att kept in LDS (both orientations), then both xa GEMMs ----------
// x1a[b,i,d] = sum_j att[i][j]*aWT[d][j]; x2a[b,i,d] = sum_j att[j][i]*aWT[d][j]
template<int D>
__global__ __launch_bounds__(256) void k_attxa(const f16* __restrict__ X1,
                                               const f16* __restrict__ X2,
                                               const f16* __restrict__ aWT,
                                               f16* __restrict__ x1a,
                                               f16* __restrict__ x2a) {
  __shared__ half8 As[64 * 4];
  __shared__ half8 Bs[64 * 4];
  __shared__ float n1s[64], n2s[64];
  __shared__ half8 atA[64 * 8];   // att, swizzled rows of 8 chunks
  __shared__ half8 atT[64 * 8];   // att^T
  __shared__ half8 Ws[128 * 8];   // aWT tile

  const int b = blockIdx.x, tid = threadIdx.x;
  const int lane = tid & 63, wave = tid >> 6;
  const int wr = wave >> 1, wc = wave & 1;
  const int l15 = lane & 15, g = lane >> 4;
  const f16* __restrict__ x1 = X1 + (size_t)b * S * D;
  const f16* __restrict__ x2 = X2 + (size_t)b * S * D;

  // ---- phase 1: attention 64x64 ----
  floatx4 acc[2][2];
#pragma unroll
  for (int i = 0; i < 2; ++i)
#pragma unroll
    for (int j = 0; j < 2; ++j) acc[i][j] = (floatx4)0.f;
  float na1 = 0.f, na2 = 0.f;

  for (int k0 = 0; k0 < D; k0 += 32) {
    __syncthreads();
    {
      const int r = tid >> 2, c = tid & 3;
      const int p = r * 4 + (c ^ ((r >> 1) & 3));
      As[p] = *reinterpret_cast<const half8*>(x1 + (size_t)r * D + k0 + c * 8);
      Bs[p] = *reinterpret_cast<const half8*>(x2 + (size_t)r * D + k0 + c * 8);
    }
    __syncthreads();
    half8 af[2], bf[2];
#pragma unroll
    for (int fi = 0; fi < 2; ++fi) {
      const int row = wr * 32 + fi * 16 + l15;
      af[fi] = As[row * 4 + (g ^ ((row >> 1) & 3))];
    }
#pragma unroll
    for (int fj = 0; fj < 2; ++fj) {
      const int row = wc * 32 + fj * 16 + l15;
      bf[fj] = Bs[row * 4 + (g ^ ((row >> 1) & 3))];
    }
#pragma unroll
    for (int fi = 0; fi < 2; ++fi)
#pragma unroll
      for (int fj = 0; fj < 2; ++fj)
        acc[fi][fj] = __builtin_amdgcn_mfma_f32_16x16x32_f16(af[fi], bf[fj], acc[fi][fj], 0, 0, 0);
    if (tid < 64) {
      const int r = tid;
#pragma unroll
      for (int c = 0; c < 4; ++c) {
        half8 v = As[r * 4 + (c ^ ((r >> 1) & 3))];
#pragma unroll
        for (int e = 0; e < 8; ++e) { float f = (float)v[e]; na1 = fmaf(f, f, na1); }
      }
    } else if (tid >= 128 && tid < 192) {
      const int r = tid - 128;
#pragma unroll
      for (int c = 0; c < 4; ++c) {
        half8 v = Bs[r * 4 + (c ^ ((r >> 1) & 3))];
#pragma unroll
        for (int e = 0; e < 8; ++e) { float f = (float)v[e]; na2 = fmaf(f, f, na2); }
      }
    }
  }
  if (tid < 64) n1s[tid] = na1;
  if (tid >= 128 && tid < 192) n2s[tid - 128] = na2;
  __syncthreads();

  // write att values into atA/atT (swizzled, fp16 scalar writes)
  f16* atAe = reinterpret_cast<f16*>(atA);
  f16* atTe = reinterpret_cast<f16*>(atT);
#pragma unroll
  for (int fi = 0; fi < 2; ++fi)
#pragma unroll
    for (int fj = 0; fj < 2; ++fj)
#pragma unroll
      for (int r = 0; r < 4; ++r) {
        const int i = wr * 32 + fi * 16 + g * 4 + r;
        const int j = wc * 32 + fj * 16 + l15;
        float sq = fmaxf(n1s[i] + n2s[j] - 2.f * acc[fi][fj][r], 0.f);
        const f16 v = (f16)(1.f / (1.f + sqrtf(sq + EPSF)));
        atAe[(i * 8 + ((j >> 3) ^ (i & 7))) * 8 + (j & 7)] = v;
        atTe[(j * 8 + ((i >> 3) ^ (j & 7))) * 8 + (i & 7)] = v;
      }

  // ---- phase 2: xa GEMMs over n-tiles of 128 ----
  const int r0 = tid >> 3, c8 = tid & 7;
  for (int n0 = 0; n0 < D; n0 += 128) {
    __syncthreads();
#pragma unroll
    for (int p = 0; p < 4; ++p) {
      const int r = r0 + p * 32;
      Ws[r * 8 + (c8 ^ (r & 7))] =
          *reinterpret_cast<const half8*>(aWT + (size_t)(n0 + r) * 64 + c8 * 8);
    }
    __syncthreads();

    floatx4 acc1[2][4], acc2[2][4];
#pragma unroll
    for (int i = 0; i < 2; ++i)
#pragma unroll
      for (int j = 0; j < 4; ++j) { acc1[i][j] = (floatx4)0.f; acc2[i][j] = (floatx4)0.f; }

#pragma unroll
    for (int sub = 0; sub < 2; ++sub) {
      half8 a1[2], a2[2], bf[4];
#pragma unroll
      for (int i = 0; i < 2; ++i) {
        const int row = wr * 32 + i * 16 + l15;
        const int ch = sub * 4 + g;
        a1[i] = atA[row * 8 + (ch ^ (row & 7))];
        a2[i] = atT[row * 8 + (ch ^ (row & 7))];
      }
#pragma unroll
      for (int j = 0; j < 4; ++j) {
        const int row = wc * 64 + j * 16 + l15;
        const int ch = sub * 4 + g;
        bf[j] = Ws[row * 8 + (ch ^ (row & 7))];
      }
#pragma unroll
      for (int i = 0; i < 2; ++i)
#pragma unroll
        for (int j = 0; j < 4; ++j) {
          acc1[i][j] = __builtin_amdgcn_mfma_f32_16x16x32_f16(a1[i], bf[j], acc1[i][j], 0, 0, 0);
          acc2[i][j] = __builtin_amdgcn_mfma_f32_16x16x32_f16(a2[i], bf[j], acc2[i][j], 0, 0, 0);
        }
    }
#pragma unroll
    for (int i = 0; i < 2; ++i)
#pragma unroll
      for (int j = 0; j < 4; ++j)
#pragma unroll
        for (int r = 0; r < 4; ++r) {
          const int m = wr * 32 + i * 16 + g * 4 + r;
          const int d = n0 + wc * 64 + j * 16 + l15;
          x1a[((size_t)b * S + m) * D + d] = (f16)acc1[i][j][r];
          x2a[((size_t)b * S + m) * D + d] = (f16)acc2[i][j][r];
        }
  }
}

// ---------- conv as im2col MFMA GEMM: 8 waves, K-split, A-window + depth-2 B pipeline ----------
// wave = (wr, wc, p): p in {0,1} handles k32-half p of each BK=64 step; partials
// combined through LDS at the end. Fragment layouts: 16x16x32 (verified).
template<int DPC>
__global__ __launch_bounds__(512) void k_conv(const f16* __restrict__ X0,
                                              const f16* __restrict__ X1v,
                                              const f16* __restrict__ XA0,
                                              const f16* __restrict__ XA1,
                                              const f16* __restrict__ wTT,
                                              const float* __restrict__ bias,
                                              f16* __restrict__ O16_0,
                                              f16* __restrict__ O16_1) {
  constexpr int NDQ = DPC / 64;
  constexpr int NSTEP = NDQ * 14;      // ks: dq = ks/14, kc = ks%14
  constexpr int KTOT = 14 * DPC;
  __shared__ half8 Wl[2][70 * 8];      // A-window per c in {X, XA}
  __shared__ half8 B8[2][128 * 8];     // B tiles, double-buffered (reused as reduce buf)

  const int tid = threadIdx.x;
  const int bid = blockIdx.x;
  const int xcd = bid & 7, slot = bid >> 3;
  const int n0 = (xcd >> 2) * 128;
  const int w = slot * 4 + (xcd & 3);
  const int z = w & 1, mblk = w >> 1;
  const int m0 = mblk * 64;
  const f16* __restrict__ Xs  = z ? X1v : X0;
  const f16* __restrict__ XAs = z ? XA1 : XA0;
  f16* __restrict__ Out16 = z ? O16_1 : O16_0;

  const int lane = tid & 63, wave = tid >> 6;       // 8 waves
  const int wr = (wave >> 2) & 1, wc = (wave >> 1) & 1, pp = wave & 1;
  const int l15 = lane & 15, g = lane >> 4;
  const int r0 = tid >> 3, c8 = tid & 7;            // 64 rows x 8 chunks

  // A-window addressing: rows j1 = r0 (0..63), j2 = 64 + r0 (r0 < 6)
  size_t aoff[2];
  bool aval[2];
#pragma unroll
  for (int p = 0; p < 2; ++p) {
    const int j = (p == 0) ? r0 : (64 + r0);
    const int u = m0 - 6 + j;
    const int uc = u < 0 ? 0 : u;
    const int bn = uc / T70;
    const int tl = uc - bn * T70;
    aval[p] = (u >= 0) && (tl < S);
    aoff[p] = (size_t)(bn * S + tl) * DPC + (size_t)c8 * 8;
  }
  const bool has2 = (r0 < 6);
  const f16* __restrict__ bp0 = wTT + (size_t)(n0 + r0) * KTOT + (size_t)c8 * 8;
  const f16* __restrict__ bp1 = wTT + (size_t)(n0 + r0 + 64) * KTOT + (size_t)c8 * 8;

  floatx4 acc[2][4];
#pragma unroll
  for (int i = 0; i < 2; ++i)
#pragma unroll
    for (int j = 0; j < 4; ++j) acc[i][j] = (floatx4)0.f;

  half8 rA[2][2];   // [c][row-pass]
  auto aLoad = [&](int dq) {
    const size_t co = (size_t)dq * 64;
#pragma unroll
    for (int c = 0; c < 2; ++c) {
      const f16* __restrict__ src = c ? XAs : Xs;
      rA[c][0] = aval[0] ? *reinterpret_cast<const half8*>(src + aoff[0] + co)
                         : (half8)(f16)0.f;
      if (has2)
        rA[c][1] = aval[1] ? *reinterpret_cast<const half8*>(src + aoff[1] + co)
                           : (half8)(f16)0.f;
    }
  };
  auto aWrite = [&]() {
#pragma unroll
    for (int c = 0; c < 2; ++c) {
      Wl[c][r0 * 8 + (c8 ^ (r0 & 7))] = rA[c][0];
      if (has2) {
        const int j = 64 + r0;
        Wl[c][j * 8 + (c8 ^ (j & 7))] = rA[c][1];
      }
    }
  };
  auto bLoad = [&](half8* rB, int ks) {
    const int dq = ks / 14, kc = ks % 14;
    const size_t o = (size_t)kc * DPC + (size_t)dq * 64;
    rB[0] = *reinterpret_cast<const half8*>(bp0 + o);
    rB[1] = *reinterpret_cast<const half8*>(bp1 + o);
  };
  auto bWrite = [&](const half8* rB, int buf) {
    B8[buf][r0 * 8 + (c8 ^ (r0 & 7))] = rB[0];
    const int r = r0 + 64;
    B8[buf][r * 8 + (c8 ^ (r & 7))] = rB[1];
  };
  auto compute = [&](int ks) {
    const int kc = ks % 14, k = kc >> 1, c = kc & 1;
    const int buf = ks & 1;
    const int ch = pp * 4 + g;
    half8 af[2], bf[4];
#pragma unroll
    for (int i = 0; i < 2; ++i) {
      const int j = wr * 32 + i * 16 + l15 + k;
      af[i] = Wl[c][j * 8 + (ch ^ (j & 7))];
    }
#pragma unroll
    for (int jx = 0; jx < 4; ++jx) {
      const int row = wc * 64 + jx * 16 + l15;
      bf[jx] = B8[buf][row * 8 + (ch ^ (row & 7))];
    }
#pragma unroll
    for (int i = 0; i < 2; ++i)
#pragma unroll
      for (int jx = 0; jx < 4; ++jx)
        acc[i][jx] = __builtin_amdgcn_mfma_f32_16x16x32_f16(af[i], bf[jx], acc[i][jx], 0, 0, 0);
  };

  half8 rBa[2], rBb[2];
  aLoad(0);
  bLoad(rBa, 0);
  aWrite();
  bWrite(rBa, 0);
  bLoad(rBa, 1);
  __syncthreads();

  auto body = [&](int ks, half8* rCur, half8* rNxt) {
    if (ks + 2 < NSTEP) bLoad(rNxt, ks + 2);
    if ((ks % 14) == 12 && (ks / 14 + 1) < NDQ) aLoad(ks / 14 + 1);
    compute(ks);
    if (ks + 1 < NSTEP) {
      if (((ks + 1) % 14) == 0) { __syncthreads(); aWrite(); }
      bWrite(rCur, (ks + 1) & 1);
    }
    __syncthreads();
  };
  for (int ks2 = 0; ks2 < NSTEP; ks2 += 2) {
    body(ks2, rBa, rBb);
    body(ks2 + 1, rBb, rBa);
  }

  // K-split reduce: p=1 partials -> LDS (lane-major, conflict-free), p=0 adds + tanh + store
  floatx4* red = reinterpret_cast<floatx4*>(&B8[0][0]);   // 8 slots * 256 = 32KB
  const int pair = wr * 2 + wc;
  if (pp) {
#pragma unroll
    for (int i = 0; i < 2; ++i)
#pragma unroll
      for (int j = 0; j < 4; ++j)
        red[(i * 4 + j) * 256 + pair * 64 + lane] = acc[i][j];
  }
  __syncthreads();
  if (!pp) {
#pragma unroll
    for (int i = 0; i < 2; ++i) {
      const int mr = m0 + wr * 32 + i * 16 + g * 4;
#pragma unroll
      for (int j = 0; j < 4; ++j) {
        const int h = n0 + wc * 64 + j * 16 + l15;
        const float bv = bias[h];
        const floatx4 o = acc[i][j] + red[(i * 4 + j) * 256 + pair * 64 + lane];
#pragma unroll
        for (int r = 0; r < 4; ++r)
          Out16[(size_t)(mr + r) * H + h] = (f16)tanhf(o[r] + bv);
      }
    }
  }
}

// ---------- fused all-pool mean + attention-weighted window pool ----------
__global__ __launch_bounds__(256) void k_powl(const f16* __restrict__ lcTh,
                                              const f16* __restrict__ rcTh,
                                              const float* __restrict__ la,
                                              const float* __restrict__ ra,
                                              float* __restrict__ LO1,
                                              float* __restrict__ RO1,
                                              f16* __restrict__ LI1h,
                                              f16* __restrict__ RI1h) {
  const int b = blockIdx.x, side = blockIdx.y;
  const f16* __restrict__ xc = (side ? rcTh : lcTh) + (size_t)b * T70 * H;
  const float* __restrict__ av = (side ? ra : la) + (size_t)b * T70;
  float* __restrict__ LO = side ? RO1 : LO1;
  f16* __restrict__ LI = (side ? RI1h : LI1h) + (size_t)b * S * H;
  __shared__ float a_s[T70];
  __shared__ f16 wv[T70][H];
  const int h = threadIdx.x;
  if (h < T70) a_s[h] = av[h];
  __syncthreads();
  float sum = 0.f;
  for (int t = 0; t < T70; ++t) {
    const float v = (float)xc[(size_t)t * H + h];
    sum += v;
    wv[t][h] = (f16)(v * a_s[t]);
  }
  LO[(size_t)b * H + h] = sum * (1.f / T70);
  __syncthreads();
  for (int s = 0; s < S; ++s) {
    float acc = 0.f;
#pragma unroll
    for (int j = 0; j < KW; ++j) acc += (float)wv[s + j][h];
    LI[(size_t)s * H + h] = (f16)acc;
  }
}

// ---------- cosine sims + final tiny GEMM ----------
__global__ __launch_bounds__(256) void k_final(const float* __restrict__ LO0,
                                               const float* __restrict__ RO0,
                                               const float* __restrict__ LO1,
                                               const float* __restrict__ RO1,
                                               const float* __restrict__ LO2,
                                               const float* __restrict__ RO2,
                                               const float* __restrict__ out_w,
                                               const float* __restrict__ out_b,
                                               float* __restrict__ out) {
  const int b = blockIdx.x;
  const int tid = threadIdx.x;
  __shared__ float red[3][4];
  __shared__ float sims[3];
  const float* Ls[3] = {LO0 + (size_t)b * D0, LO1 + (size_t)b * H, LO2 + (size_t)b * H};
  const float* Rs[3] = {RO0 + (size_t)b * D0, RO1 + (size_t)b * H, RO2 + (size_t)b * H};
  const int dims[3] = {D0, H, H};
#pragma unroll
  for (int p = 0; p < 3; ++p) {
    float dot = 0.f, q1 = 0.f, q2 = 0.f;
    for (int i = tid; i < dims[p]; i += 256) {
      const float v1 = Ls[p][i], v2 = Rs[p][i];
      dot = fmaf(v1, v2, dot);
      q1  = fmaf(v1, v1, q1);
      q2  = fmaf(v2, v2, q2);
    }
#pragma unroll
    for (int off = 32; off > 0; off >>= 1) {
      dot += __shfl_down(dot, off);
      q1  += __shfl_down(q1, off);
      q2  += __shfl_down(q2, off);
    }
    if ((tid & 63) == 0) { red[0][tid >> 6] = dot; red[1][tid >> 6] = q1; red[2][tid >> 6] = q2; }
    __syncthreads();
    if (tid == 0) {
      float d = red[0][0] + red[0][1] + red[0][2] + red[0][3];
      float a = red[1][0] + red[1][1] + red[1][2] + red[1][3];
      float c = red[2][0] + red[2][1] + red[2][2] + red[2][3];
      sims[p] = d / (sqrtf(a) * sqrtf(c) + EPSF);
    }
    __syncthreads();
  }
  if (tid < NC) {
    float v = out_b[tid];
#pragma unroll
    for (int k = 0; k < 3; ++k) v = fmaf(sims[k], out_w[k * NC + tid], v);
    out[b * NC + tid] = v;
  }
}

extern "C" void kernel_launch(void* const* d_in, const int* in_sizes, int n_in,
                              void* d_out, int out_size, void* d_ws, size_t ws_size,
                              hipStream_t stream) {
  const float* premise    = (const float*)d_in[0];
  const float* hypothesis = (const float*)d_in[1];
  const float* aW1        = (const float*)d_in[2];
  const float* conv1_w    = (const float*)d_in[3];
  const float* conv1_b    = (const float*)d_in[4];
  const float* aW2        = (const float*)d_in[5];
  const float* conv2_w    = (const float*)d_in[6];
  const float* conv2_b    = (const float*)d_in[7];
  const float* out_w      = (const float*)d_in[8];
  const float* out_b      = (const float*)d_in[9];
  float* out = (float*)d_out;

  char* ws = (char*)d_ws;
  size_t off = 0;
  auto alloc = [&](size_t bytes) {
    void* p = ws + off;
    off += (bytes + 255) & ~(size_t)255;
    return p;
  };
  f16*   wTT1  = (f16*)alloc((size_t)14 * D0 * H * 2);
  f16*   wTT2  = (f16*)alloc((size_t)14 * H * H * 2);
  f16*   aWT1  = (f16*)alloc((size_t)D0 * 64 * 2);
  f16*   aWT2  = (f16*)alloc((size_t)H * 64 * 2);
  f16*   Xh    = (f16*)alloc((size_t)B * S * D0 * 2);
  f16*   Yh    = (f16*)alloc((size_t)B * S * D0 * 2);
  f16*   x1ah  = (f16*)alloc((size_t)B * S * D0 * 2);   // layer2 output aliases prefix
  f16*   x2ah  = (f16*)alloc((size_t)B * S * D0 * 2);
  f16*   LI1h  = (f16*)alloc((size_t)B * S * H * 2);
  f16*   RI1h  = (f16*)alloc((size_t)B * S * H * 2);
  f16*   lcTh  = (f16*)alloc((size_t)B * T70 * H * 2);  // reused layer2
  f16*   rcTh  = (f16*)alloc((size_t)B * T70 * H * 2);
  float* LO0   = (float*)alloc((size_t)B * D0 * 4);
  float* RO0   = (float*)alloc((size_t)B * D0 * 4);
  float* LO1   = (float*)alloc((size_t)B * H * 4);
  float* RO1   = (float*)alloc((size_t)B * H * 4);
  float* LO2   = (float*)alloc((size_t)B * H * 4);
  float* RO2   = (float*)alloc((size_t)B * H * 4);
  float* la    = (float*)alloc((size_t)B * T70 * 4);
  float* ra    = (float*)alloc((size_t)B * T70 * 4);

  // 0. fused converts+means (both sides), weight transposes
  k_cvtmean<<<dim3(B * (D0 / 4) / 256, 2), 256, 0, stream>>>(premise, hypothesis, Xh, Yh, LO0, RO0);
  k_trw<<<dim3(D0 / 64, H / 64, 14), 256, 0, stream>>>(conv1_w, wTT1, D0, 14 * D0);
  k_trw<<<dim3(H / 64,  H / 64, 14), 256, 0, stream>>>(conv2_w, wTT2, H, 14 * H);
  k_trw_aw<<<D0 / 64, 256, 0, stream>>>(aW1, aWT1, D0);
  k_trw_aw<<<H  / 64, 256, 0, stream>>>(aW2, aWT2, H);
  // 1. fused att1 + xa1
  k_attxa<D0><<<B, 256, 0, stream>>>(Xh, Yh, aWT1, x1ah, x2ah);
  // 2. conv1 (8-wave K-split) -> lcTh/rcTh fp16
  k_conv<D0><<<560, 512, 0, stream>>>(Xh, Yh, x1ah, x2ah, wTT1, conv1_b, lcTh, rcTh);
  // 3. att2 sums
  k_att<T70, 96, H, false, true><<<B, 256, 0, stream>>>(lcTh, rcTh, nullptr, nullptr, la, ra);
  // 4. fused mean + wpool
  k_powl<<<dim3(B, 2), 256, 0, stream>>>(lcTh, rcTh, la, ra, LO1, RO1, LI1h, RI1h);
  // 5. fused att2' + xa2
  k_attxa<H><<<B, 256, 0, stream>>>(LI1h, RI1h, aWT2, x1ah, x2ah);
  // 6. conv2 -> reuse lcTh/rcTh
  k_conv<H><<<560, 512, 0, stream>>>(LI1h, RI1h, x1ah, x2ah, wTT2, conv2_b, lcTh, rcTh);
  // 7. LO2/RO2 (merged)
  k_mean2<<<dim3((B * H + 255) / 256, 2), 256, 0, stream>>>(lcTh, rcTh, LO2, RO2);
  // 8. final
  k_final<<<B, 256, 0, stream>>>(LO0, RO0, LO1, RO1, LO2, RO2, out_w, out_b, out);
}

// Round 6
// 287.804 us; speedup vs baseline: 18.4580x; 1.1620x over previous
//
#include <hip/hip_runtime.h>
#include <math.h>

typedef _Float16 f16;
typedef _Float16 half8 __attribute__((ext_vector_type(8)));
typedef _Float16 half4 __attribute__((ext_vector_type(4)));
typedef float floatx4 __attribute__((ext_vector_type(4)));

constexpr int B   = 128;
constexpr int S   = 64;
constexpr int D0  = 768;
constexpr int H   = 256;
constexpr int KW  = 7;
constexpr int NC  = 3;
constexpr int T70 = S + KW - 1;  // 70
constexpr float EPSF = 1e-12f;

// global_load_lds width=16: linear LDS dest (wave-uniform base + lane*16), per-lane global src
__device__ __forceinline__ void gload16(const void* g, void* l) {
  __builtin_amdgcn_global_load_lds(
      (const __attribute__((address_space(1))) unsigned int*)g,
      (__attribute__((address_space(3))) unsigned int*)l, 16, 0, 0);
}

// ---------- fused fp32->fp16 convert + mean over t, both sides ----------
__global__ __launch_bounds__(256) void k_cvtmean(const float* __restrict__ in0,
                                                 const float* __restrict__ in1,
                                                 f16* __restrict__ oh0,
                                                 f16* __restrict__ oh1,
                                                 float* __restrict__ mn0,
                                                 float* __restrict__ mn1) {
  constexpr int D4 = D0 / 4;
  const int side = blockIdx.y;
  const float* __restrict__ in = side ? in1 : in0;
  f16* __restrict__ outh = side ? oh1 : oh0;
  float* __restrict__ mean = side ? mn1 : mn0;
  const int idx = blockIdx.x * 256 + threadIdx.x;   // grid.x = B*D4/256 = 96
  const int b = idx / D4, f4 = idx % D4;
  const float4* __restrict__ src = reinterpret_cast<const float4*>(in) + (size_t)b * S * D4 + f4;
  half4* __restrict__ dst = reinterpret_cast<half4*>(outh) + (size_t)b * S * D4 + f4;
  float4 acc = {0.f, 0.f, 0.f, 0.f};
  for (int t = 0; t < S; ++t) {
    float4 v = src[(size_t)t * D4];
    acc.x += v.x; acc.y += v.y; acc.z += v.z; acc.w += v.w;
    half4 o = {(f16)v.x, (f16)v.y, (f16)v.z, (f16)v.w};
    dst[(size_t)t * D4] = o;
  }
  const float inv = 1.f / S;
  mean[(size_t)b * D0 + f4 * 4 + 0] = acc.x * inv;
  mean[(size_t)b * D0 + f4 * 4 + 1] = acc.y * inv;
  mean[(size_t)b * D0 + f4 * 4 + 2] = acc.z * inv;
  mean[(size_t)b * D0 + f4 * 4 + 3] = acc.w * inv;
}

// ---------- conv weight transpose, PRE-SWIZZLED: ----------
// Wsz[h][chunk c] = wTT[h][chunk c ^ (h&7)] so linear global_load_lds + swizzled
// ds_read (chunk ch^(r&7)) recovers wTT[h][ch].  (chunk = 8 f16 = 16B)
__global__ __launch_bounds__(256) void k_trw(const float* __restrict__ cw,
                                             f16* __restrict__ wTT, int DPC, int Ktot) {
  __shared__ f16 tile[64][65];
  const int kc = blockIdx.z, k = kc >> 1, c = kc & 1;
  const int dd0 = blockIdx.x * 64, h0 = blockIdx.y * 64;
  const int tx = threadIdx.x & 63, ty = threadIdx.x >> 6;
#pragma unroll
  for (int i = 0; i < 64; i += 4) {
    int dd = dd0 + i + ty;
    tile[i + ty][tx] = (f16)cw[(size_t)((dd * KW + k) * 2 + c) * H + h0 + tx];
  }
  __syncthreads();
#pragma unroll
  for (int i = 0; i < 64; i += 4) {
    int h = h0 + i + ty;
    // swizzle: within this 64-col group, chunk (tx>>3) goes to chunk (tx>>3)^(h&7)
    int col = (size_t)kc * DPC + dd0 + (((tx >> 3) ^ (h & 7)) << 3) + (tx & 7);
    wTT[(size_t)h * Ktot + col] = tile[tx][i + ty];
  }
}

// ---------- aW[S=64][D] fp32 -> aWT[D][64] fp16 ----------
__global__ __launch_bounds__(256) void k_trw_aw(const float* __restrict__ aW,
                                                f16* __restrict__ aWT, int D) {
  __shared__ f16 tile[64][65];
  const int d0 = blockIdx.x * 64;
  const int tx = threadIdx.x & 63, ty = threadIdx.x >> 6;
#pragma unroll
  for (int i = 0; i < 64; i += 4) {
    int s = i + ty;
    tile[s][tx] = (f16)aW[(size_t)s * D + d0 + tx];
  }
  __syncthreads();
#pragma unroll
  for (int i = 0; i < 64; i += 4) {
    int d = i + ty;
    aWT[(size_t)(d0 + d) * 64 + tx] = tile[tx][d];
  }
}

// ---------- merged means over axis 1 of [B,70,H] fp16 -> [B,H] fp32, 2 sides ----------
__global__ __launch_bounds__(256) void k_mean2(const f16* __restrict__ xa,
                                               const f16* __restrict__ xb,
                                               float* __restrict__ oa,
                                               float* __restrict__ ob) {
  const int side = blockIdx.y;
  const f16* __restrict__ x = side ? xb : xa;
  float* __restrict__ o = side ? ob : oa;
  int idx = blockIdx.x * 256 + threadIdx.x;
  if (idx >= B * H) return;
  int b = idx / H, f = idx % H;
  const f16* p = x + (size_t)b * T70 * H + f;
  float s = 0.f;
  for (int t = 0; t < T70; ++t) s += (float)p[(size_t)t * H];
  o[idx] = s * (1.f / T70);
}

// ---------- MFMA attention (generic, used for att2 sums) ----------
template<int W, int WP, int D, bool STORE, bool SUMS>
__global__ __launch_bounds__(256) void k_att(const f16* __restrict__ X1,
                                             const f16* __restrict__ X2,
                                             f16* __restrict__ attA,
                                             f16* __restrict__ attT,
                                             float* __restrict__ la,
                                             float* __restrict__ ra) {
  constexpr int FR = WP / 32;
  __shared__ half8 As[WP * 4];
  __shared__ half8 Bs[WP * 4];
  __shared__ float n1s[WP], n2s[WP];
  __shared__ float att_s[SUMS ? WP * (WP + 1) : 1];

  const int b = blockIdx.x, tid = threadIdx.x;
  const int lane = tid & 63, wave = tid >> 6;
  const int wr = wave >> 1, wc = wave & 1;
  const int l15 = lane & 15, g = lane >> 4;
  const f16* __restrict__ x1 = X1 + (size_t)b * W * D;
  const f16* __restrict__ x2 = X2 + (size_t)b * W * D;

  floatx4 acc[FR][FR];
#pragma unroll
  for (int i = 0; i < FR; ++i)
#pragma unroll
    for (int j = 0; j < FR; ++j) acc[i][j] = (floatx4)0.f;
  float na1 = 0.f, na2 = 0.f;

  for (int k0 = 0; k0 < D; k0 += 32) {
    __syncthreads();
    for (int u = tid; u < WP * 4; u += 256) {
      const int r = u >> 2, c = u & 3;
      half8 v1 = (half8)(f16)0.f, v2 = (half8)(f16)0.f;
      if (r < W) {
        v1 = *reinterpret_cast<const half8*>(x1 + (size_t)r * D + k0 + c * 8);
        v2 = *reinterpret_cast<const half8*>(x2 + (size_t)r * D + k0 + c * 8);
      }
      const int p = r * 4 + (c ^ ((r >> 1) & 3));
      As[p] = v1;
      Bs[p] = v2;
    }
    __syncthreads();
    half8 af[FR], bf[FR];
#pragma unroll
    for (int fi = 0; fi < FR; ++fi) {
      const int row = wr * 16 * FR + fi * 16 + l15;
      af[fi] = As[row * 4 + (g ^ ((row >> 1) & 3))];
    }
#pragma unroll
    for (int fj = 0; fj < FR; ++fj) {
      const int row = wc * 16 * FR + fj * 16 + l15;
      bf[fj] = Bs[row * 4 + (g ^ ((row >> 1) & 3))];
    }
#pragma unroll
    for (int fi = 0; fi < FR; ++fi)
#pragma unroll
      for (int fj = 0; fj < FR; ++fj)
        acc[fi][fj] = __builtin_amdgcn_mfma_f32_16x16x32_f16(af[fi], bf[fj], acc[fi][fj], 0, 0, 0);
    if (tid < WP) {
      const int r = tid;
#pragma unroll
      for (int c = 0; c < 4; ++c) {
        half8 v = As[r * 4 + (c ^ ((r >> 1) & 3))];
#pragma unroll
        for (int e = 0; e < 8; ++e) { float f = (float)v[e]; na1 = fmaf(f, f, na1); }
      }
    } else if (tid >= 128 && tid < 128 + WP) {
      const int r = tid - 128;
#pragma unroll
      for (int c = 0; c < 4; ++c) {
        half8 v = Bs[r * 4 + (c ^ ((r >> 1) & 3))];
#pragma unroll
        for (int e = 0; e < 8; ++e) { float f = (float)v[e]; na2 = fmaf(f, f, na2); }
      }
    }
  }
  if (tid < WP) n1s[tid] = na1;
  if (tid >= 128 && tid < 128 + WP) n2s[tid - 128] = na2;
  __syncthreads();

#pragma unroll
  for (int fi = 0; fi < FR; ++fi)
#pragma unroll
    for (int fj = 0; fj < FR; ++fj)
#pragma unroll
      for (int r = 0; r < 4; ++r) {
        const int i = wr * 16 * FR + fi * 16 + g * 4 + r;
        const int j = wc * 16 * FR + fj * 16 + l15;
        if (i < W && j < W) {
          float sq = fmaxf(n1s[i] + n2s[j] - 2.f * acc[fi][fj][r], 0.f);
          const float v = 1.f / (1.f + sqrtf(sq + EPSF));
          if (STORE) {
            attA[((size_t)b * W + i) * W + j] = (f16)v;
            attT[((size_t)b * W + j) * W + i] = (f16)v;
          }
          if (SUMS) att_s[i * (WP + 1) + j] = v;
        }
      }
  if (SUMS) {
    __syncthreads();
    if (tid < W) {
      float sum = 0.f;
      for (int j = 0; j < W; ++j) sum += att_s[tid * (WP + 1) + j];
      la[b * W + tid] = sum;
    }
    if (tid >= 128 && tid < 128 + W) {
      const int j = tid - 128;
      float sum = 0.f;
      for (int i = 0; i < W; ++i) sum += att_s[i * (WP + 1) + j];
      ra[b * W + j] = sum;
    }
  }
}

// ---------- FUSED att + xa: att kept in LDS (both orientations), then both xa GEMMs ----------
template<int D>
__global__ __launch_bounds__(256) void k_attxa(const f16* __restrict__ X1,
                                               const f16* __restrict__ X2,
                                               const f16* __restrict__ aWT,
                                               f16* __restrict__ x1a,
                                               f16* __restrict__ x2a) {
  __shared__ half8 As[64 * 4];
  __shared__ half8 Bs[64 * 4];
  __shared__ float n1s[64], n2s[64];
  __shared__ half8 atA[64 * 8];
  __shared__ half8 atT[64 * 8];
  __shared__ half8 Ws[128 * 8];

  const int b = blockIdx.x, tid = threadIdx.x;
  const int lane = tid & 63, wave = tid >> 6;
  const int wr = wave >> 1, wc = wave & 1;
  const int l15 = lane & 15, g = lane >> 4;
  const f16* __restrict__ x1 = X1 + (size_t)b * S * D;
  const f16* __restrict__ x2 = X2 + (size_t)b * S * D;

  floatx4 acc[2][2];
#pragma unroll
  for (int i = 0; i < 2; ++i)
#pragma unroll
    for (int j = 0; j < 2; ++j) acc[i][j] = (floatx4)0.f;
  float na1 = 0.f, na2 = 0.f;

  for (int k0 = 0; k0 < D; k0 += 32) {
    __syncthreads();
    {
      const int r = tid >> 2, c = tid & 3;
      const int p = r * 4 + (c ^ ((r >> 1) & 3));
      As[p] = *reinterpret_cast<const half8*>(x1 + (size_t)r * D + k0 + c * 8);
      Bs[p] = *reinterpret_cast<const half8*>(x2 + (size_t)r * D + k0 + c * 8);
    }
    __syncthreads();
    half8 af[2], bf[2];
#pragma unroll
    for (int fi = 0; fi < 2; ++fi) {
      const int row = wr * 32 + fi * 16 + l15;
      af[fi] = As[row * 4 + (g ^ ((row >> 1) & 3))];
    }
#pragma unroll
    for (int fj = 0; fj < 2; ++fj) {
      const int row = wc * 32 + fj * 16 + l15;
      bf[fj] = Bs[row * 4 + (g ^ ((row >> 1) & 3))];
    }
#pragma unroll
    for (int fi = 0; fi < 2; ++fi)
#pragma unroll
      for (int fj = 0; fj < 2; ++fj)
        acc[fi][fj] = __builtin_amdgcn_mfma_f32_16x16x32_f16(af[fi], bf[fj], acc[fi][fj], 0, 0, 0);
    if (tid < 64) {
      const int r = tid;
#pragma unroll
      for (int c = 0; c < 4; ++c) {
        half8 v = As[r * 4 + (c ^ ((r >> 1) & 3))];
#pragma unroll
        for (int e = 0; e < 8; ++e) { float f = (float)v[e]; na1 = fmaf(f, f, na1); }
      }
    } else if (tid >= 128 && tid < 192) {
      const int r = tid - 128;
#pragma unroll
      for (int c = 0; c < 4; ++c) {
        half8 v = Bs[r * 4 + (c ^ ((r >> 1) & 3))];
#pragma unroll
        for (int e = 0; e < 8; ++e) { float f = (float)v[e]; na2 = fmaf(f, f, na2); }
      }
    }
  }
  if (tid < 64) n1s[tid] = na1;
  if (tid >= 128 && tid < 192) n2s[tid - 128] = na2;
  __syncthreads();

  f16* atAe = reinterpret_cast<f16*>(atA);
  f16* atTe = reinterpret_cast<f16*>(atT);
#pragma unroll
  for (int fi = 0; fi < 2; ++fi)
#pragma unroll
    for (int fj = 0; fj < 2; ++fj)
#pragma unroll
      for (int r = 0; r < 4; ++r) {
        const int i = wr * 32 + fi * 16 + g * 4 + r;
        const int j = wc * 32 + fj * 16 + l15;
        float sq = fmaxf(n1s[i] + n2s[j] - 2.f * acc[fi][fj][r], 0.f);
        const f16 v = (f16)(1.f / (1.f + sqrtf(sq + EPSF)));
        atAe[(i * 8 + ((j >> 3) ^ (i & 7))) * 8 + (j & 7)] = v;
        atTe[(j * 8 + ((i >> 3) ^ (j & 7))) * 8 + (i & 7)] = v;
      }

  const int r0 = tid >> 3, c8 = tid & 7;
  for (int n0 = 0; n0 < D; n0 += 128) {
    __syncthreads();
#pragma unroll
    for (int p = 0; p < 4; ++p) {
      const int r = r0 + p * 32;
      Ws[r * 8 + (c8 ^ (r & 7))] =
          *reinterpret_cast<const half8*>(aWT + (size_t)(n0 + r) * 64 + c8 * 8);
    }
    __syncthreads();

    floatx4 acc1[2][4], acc2[2][4];
#pragma unroll
    for (int i = 0; i < 2; ++i)
#pragma unroll
      for (int j = 0; j < 4; ++j) { acc1[i][j] = (floatx4)0.f; acc2[i][j] = (floatx4)0.f; }

#pragma unroll
    for (int sub = 0; sub < 2; ++sub) {
      half8 a1[2], a2[2], bf[4];
#pragma unroll
      for (int i = 0; i < 2; ++i) {
        const int row = wr * 32 + i * 16 + l15;
        const int ch = sub * 4 + g;
        a1[i] = atA[row * 8 + (ch ^ (row & 7))];
        a2[i] = atT[row * 8 + (ch ^ (row & 7))];
      }
#pragma unroll
      for (int j = 0; j < 4; ++j) {
        const int row = wc * 64 + j * 16 + l15;
        const int ch = sub * 4 + g;
        bf[j] = Ws[row * 8 + (ch ^ (row & 7))];
      }
#pragma unroll
      for (int i = 0; i < 2; ++i)
#pragma unroll
        for (int j = 0; j < 4; ++j) {
          acc1[i][j] = __builtin_amdgcn_mfma_f32_16x16x32_f16(a1[i], bf[j], acc1[i][j], 0, 0, 0);
          acc2[i][j] = __builtin_amdgcn_mfma_f32_16x16x32_f16(a2[i], bf[j], acc2[i][j], 0, 0, 0);
        }
    }
#pragma unroll
    for (int i = 0; i < 2; ++i)
#pragma unroll
      for (int j = 0; j < 4; ++j)
#pragma unroll
        for (int r = 0; r < 4; ++r) {
          const int m = wr * 32 + i * 16 + g * 4 + r;
          const int d = n0 + wc * 64 + j * 16 + l15;
          x1a[((size_t)b * S + m) * D + d] = (f16)acc1[i][j][r];
          x2a[((size_t)b * S + m) * D + d] = (f16)acc2[i][j][r];
        }
  }
}

// ---------- conv: 4 waves, A-window reg-staged, B via global_load_lds (pre-swz weights) ----------
template<int DPC>
__global__ __launch_bounds__(256) void k_conv(const f16* __restrict__ X0,
                                              const f16* __restrict__ X1v,
                                              const f16* __restrict__ XA0,
                                              const f16* __restrict__ XA1,
                                              const f16* __restrict__ Wsz,
                                              const float* __restrict__ bias,
                                              f16* __restrict__ O16_0,
                                              f16* __restrict__ O16_1) {
  constexpr int NDQ = DPC / 64;
  constexpr int NSTEP = NDQ * 14;      // ks: dq = ks/14, kc = ks%14
  constexpr int KTOT = 14 * DPC;
  __shared__ half8 Wl[2][70 * 8];      // A-window per c in {X, XA}
  __shared__ half8 B8[2][128 * 8];     // B tiles, double-buffered (linear layout)

  const int tid = threadIdx.x;
  const int bid = blockIdx.x;
  const int xcd = bid & 7, slot = bid >> 3;
  const int n0 = (xcd >> 2) * 128;
  const int w = slot * 4 + (xcd & 3);
  const int z = w & 1, mblk = w >> 1;
  const int m0 = mblk * 64;
  const f16* __restrict__ Xs  = z ? X1v : X0;
  const f16* __restrict__ XAs = z ? XA1 : XA0;
  f16* __restrict__ Out16 = z ? O16_1 : O16_0;

  const int lane = tid & 63, wave = tid >> 6;       // 4 waves
  const int wr = wave >> 1, wc = wave & 1;
  const int l15 = lane & 15, g = lane >> 4;
  const int r0 = tid >> 3, c8 = tid & 7;            // A staging roles (32 rows x 8 chunks)

  // A-window addressing: rows j = r0, r0+32, 64+r0 (r0 < 6)
  int jr[3] = {r0, r0 + 32, 64 + r0};
  size_t aoff[3];
  bool aval[3];
#pragma unroll
  for (int p = 0; p < 3; ++p) {
    const int u = m0 - 6 + jr[p];
    const int uc = u < 0 ? 0 : u;
    const int bn = uc / T70;
    const int tl = uc - bn * T70;
    aval[p] = (u >= 0) && (tl < S);
    aoff[p] = (size_t)(bn * S + tl) * DPC + (size_t)c8 * 8;
  }
  const bool has2 = (r0 < 6);
  // B gload: each lane covers chunk (q*256 + wave*64 + lane), q=0..3 -> row chunk>>3, col chunk&7
  const int bchunk0 = wave * 64 + lane;
  const f16* __restrict__ bsrc = Wsz + (size_t)n0 * KTOT;

  floatx4 acc[2][4];
#pragma unroll
  for (int i = 0; i < 2; ++i)
#pragma unroll
    for (int j = 0; j < 4; ++j) acc[i][j] = (floatx4)0.f;

  half8 rA[2][3];
  auto aLoad = [&](int dq) {
    const size_t co = (size_t)dq * 64;
#pragma unroll
    for (int c = 0; c < 2; ++c) {
      const f16* __restrict__ src = c ? XAs : Xs;
#pragma unroll
      for (int p = 0; p < 2; ++p)
        rA[c][p] = aval[p] ? *reinterpret_cast<const half8*>(src + aoff[p] + co)
                           : (half8)(f16)0.f;
      if (has2)
        rA[c][2] = aval[2] ? *reinterpret_cast<const half8*>(src + aoff[2] + co)
                           : (half8)(f16)0.f;
    }
  };
  auto aWrite = [&]() {
#pragma unroll
    for (int c = 0; c < 2; ++c) {
#pragma unroll
      for (int p = 0; p < 2; ++p) {
        const int j = jr[p];
        Wl[c][j * 8 + (c8 ^ (j & 7))] = rA[c][p];
      }
      if (has2) {
        const int j = jr[2];
        Wl[c][j * 8 + (c8 ^ (j & 7))] = rA[c][2];
      }
    }
  };
  auto bStage = [&](int buf, int ks) {
    const int dq = ks / 14, kc = ks % 14;
    const size_t o = (size_t)kc * DPC + (size_t)dq * 64;
#pragma unroll
    for (int q = 0; q < 4; ++q) {
      const int chunk = q * 256 + bchunk0;
      const int r = chunk >> 3, cc = chunk & 7;
      gload16(bsrc + (size_t)r * KTOT + o + cc * 8, &B8[buf][q * 256 + wave * 64]);
    }
  };
  auto compute = [&](int ks) {
    const int kc = ks % 14, k = kc >> 1, c = kc & 1;
    const int buf = ks & 1;
    half8 af[2][2], bf[4][2];
#pragma unroll
    for (int i = 0; i < 2; ++i) {
      const int j = wr * 32 + i * 16 + l15 + k;
#pragma unroll
      for (int sub = 0; sub < 2; ++sub)
        af[i][sub] = Wl[c][j * 8 + ((sub * 4 + g) ^ (j & 7))];
    }
#pragma unroll
    for (int jx = 0; jx < 4; ++jx) {
      const int row = wc * 64 + jx * 16 + l15;
#pragma unroll
      for (int sub = 0; sub < 2; ++sub)
        bf[jx][sub] = B8[buf][row * 8 + ((sub * 4 + g) ^ (row & 7))];
    }
#pragma unroll
    for (int sub = 0; sub < 2; ++sub)
#pragma unroll
      for (int i = 0; i < 2; ++i)
#pragma unroll
        for (int jx = 0; jx < 4; ++jx)
          acc[i][jx] = __builtin_amdgcn_mfma_f32_16x16x32_f16(af[i][sub], bf[jx][sub], acc[i][jx], 0, 0, 0);
  };

  // prologue: A(dq0) regs->LDS, B(step0) direct-to-LDS
  aLoad(0);
  bStage(0, 0);
  aWrite();
  __syncthreads();   // drains vmcnt(0) + lgkmcnt(0)

  for (int ks = 0; ks < NSTEP; ++ks) {
    const int nxt = ks + 1;
    const bool more = nxt < NSTEP;
    if (more) {
      bStage(nxt & 1, nxt);                 // async, lands by end-of-step barrier
      if (nxt % 14 == 0) aLoad(nxt / 14);   // global->reg, covered by compute
    }
    compute(ks);
    if (more && (nxt % 14 == 0)) { __syncthreads(); aWrite(); }
    __syncthreads();
  }

  // epilogue: fused bias + tanh, fp16 store
#pragma unroll
  for (int i = 0; i < 2; ++i) {
    const int mr = m0 + wr * 32 + i * 16 + g * 4;
#pragma unroll
    for (int j = 0; j < 4; ++j) {
      const int h = n0 + wc * 64 + j * 16 + l15;
      const float bv = bias[h];
#pragma unroll
      for (int r = 0; r < 4; ++r)
        Out16[(size_t)(mr + r) * H + h] = (f16)tanhf(acc[i][j][r] + bv);
    }
  }
}

// ---------- fused all-pool mean + attention-weighted window pool ----------
__global__ __launch_bounds__(256) void k_powl(const f16* __restrict__ lcTh,
                                              const f16* __restrict__ rcTh,
                                              const float* __restrict__ la,
                                              const float* __restrict__ ra,
                                              float* __restrict__ LO1,
                                              float* __restrict__ RO1,
                                              f16* __restrict__ LI1h,
                                              f16* __restrict__ RI1h) {
  const int b = blockIdx.x, side = blockIdx.y;
  const f16* __restrict__ xc = (side ? rcTh : lcTh) + (size_t)b * T70 * H;
  const float* __restrict__ av = (side ? ra : la) + (size_t)b * T70;
  float* __restrict__ LO = side ? RO1 : LO1;
  f16* __restrict__ LI = (side ? RI1h : LI1h) + (size_t)b * S * H;
  __shared__ float a_s[T70];
  __shared__ f16 wv[T70][H];
  const int h = threadIdx.x;
  if (h < T70) a_s[h] = av[h];
  __syncthreads();
  float sum = 0.f;
  for (int t = 0; t < T70; ++t) {
    const float v = (float)xc[(size_t)t * H + h];
    sum += v;
    wv[t][h] = (f16)(v * a_s[t]);
  }
  LO[(size_t)b * H + h] = sum * (1.f / T70);
  __syncthreads();
  for (int s = 0; s < S; ++s) {
    float acc = 0.f;
#pragma unroll
    for (int j = 0; j < KW; ++j) acc += (float)wv[s + j][h];
    LI[(size_t)s * H + h] = (f16)acc;
  }
}

// ---------- cosine sims + final tiny GEMM ----------
__global__ __launch_bounds__(256) void k_final(const float* __restrict__ LO0,
                                               const float* __restrict__ RO0,
                                               const float* __restrict__ LO1,
                                               const float* __restrict__ RO1,
                                               const float* __restrict__ LO2,
                                               const float* __restrict__ RO2,
                                               const float* __restrict__ out_w,
                                               const float* __restrict__ out_b,
                                               float* __restrict__ out) {
  const int b = blockIdx.x;
  const int tid = threadIdx.x;
  __shared__ float red[3][4];
  __shared__ float sims[3];
  const float* Ls[3] = {LO0 + (size_t)b * D0, LO1 + (size_t)b * H, LO2 + (size_t)b * H};
  const float* Rs[3] = {RO0 + (size_t)b * D0, RO1 + (size_t)b * H, RO2 + (size_t)b * H};
  const int dims[3] = {D0, H, H};
#pragma unroll
  for (int p = 0; p < 3; ++p) {
    float dot = 0.f, q1 = 0.f, q2 = 0.f;
    for (int i = tid; i < dims[p]; i += 256) {
      const float v1 = Ls[p][i], v2 = Rs[p][i];
      dot = fmaf(v1, v2, dot);
      q1  = fmaf(v1, v1, q1);
      q2  = fmaf(v2, v2, q2);
    }
#pragma unroll
    for (int off = 32; off > 0; off >>= 1) {
      dot += __shfl_down(dot, off);
      q1  += __shfl_down(q1, off);
      q2  += __shfl_down(q2, off);
    }
    if ((tid & 63) == 0) { red[0][tid >> 6] = dot; red[1][tid >> 6] = q1; red[2][tid >> 6] = q2; }
    __syncthreads();
    if (tid == 0) {
      float d = red[0][0] + red[0][1] + red[0][2] + red[0][3];
      float a = red[1][0] + red[1][1] + red[1][2] + red[1][3];
      float c = red[2][0] + red[2][1] + red[2][2] + red[2][3];
      sims[p] = d / (sqrtf(a) * sqrtf(c) + EPSF);
    }
    __syncthreads();
  }
  if (tid < NC) {
    float v = out_b[tid];
#pragma unroll
    for (int k = 0; k < 3; ++k) v = fmaf(sims[k], out_w[k * NC + tid], v);
    out[b * NC + tid] = v;
  }
}

extern "C" void kernel_launch(void* const* d_in, const int* in_sizes, int n_in,
                              void* d_out, int out_size, void* d_ws, size_t ws_size,
                              hipStream_t stream) {
  const float* premise    = (const float*)d_in[0];
  const float* hypothesis = (const float*)d_in[1];
  const float* aW1        = (const float*)d_in[2];
  const float* conv1_w    = (const float*)d_in[3];
  const float* conv1_b    = (const float*)d_in[4];
  const float* aW2        = (const float*)d_in[5];
  const float* conv2_w    = (const float*)d_in[6];
  const float* conv2_b    = (const float*)d_in[7];
  const float* out_w      = (const float*)d_in[8];
  const float* out_b      = (const float*)d_in[9];
  float* out = (float*)d_out;

  char* ws = (char*)d_ws;
  size_t off = 0;
  auto alloc = [&](size_t bytes) {
    void* p = ws + off;
    off += (bytes + 255) & ~(size_t)255;
    return p;
  };
  f16*   wTT1  = (f16*)alloc((size_t)14 * D0 * H * 2);
  f16*   wTT2  = (f16*)alloc((size_t)14 * H * H * 2);
  f16*   aWT1  = (f16*)alloc((size_t)D0 * 64 * 2);
  f16*   aWT2  = (f16*)alloc((size_t)H * 64 * 2);
  f16*   Xh    = (f16*)alloc((size_t)B * S * D0 * 2);
  f16*   Yh    = (f16*)alloc((size_t)B * S * D0 * 2);
  f16*   x1ah  = (f16*)alloc((size_t)B * S * D0 * 2);   // layer2 output aliases prefix
  f16*   x2ah  = (f16*)alloc((size_t)B * S * D0 * 2);
  f16*   LI1h  = (f16*)alloc((size_t)B * S * H * 2);
  f16*   RI1h  = (f16*)alloc((size_t)B * S * H * 2);
  f16*   lcTh  = (f16*)alloc((size_t)B * T70 * H * 2);  // reused layer2
  f16*   rcTh  = (f16*)alloc((size_t)B * T70 * H * 2);
  float* LO0   = (float*)alloc((size_t)B * D0 * 4);
  float* RO0   = (float*)alloc((size_t)B * D0 * 4);
  float* LO1   = (float*)alloc((size_t)B * H * 4);
  float* RO1   = (float*)alloc((size_t)B * H * 4);
  float* LO2   = (float*)alloc((size_t)B * H * 4);
  float* RO2   = (float*)alloc((size_t)B * H * 4);
  float* la    = (float*)alloc((size_t)B * T70 * 4);
  float* ra    = (float*)alloc((size_t)B * T70 * 4);

  // 0. fused converts+means (both sides), weight transposes (pre-swizzled)
  k_cvtmean<<<dim3(B * (D0 / 4) / 256, 2), 256, 0, stream>>>(premise, hypothesis, Xh, Yh, LO0, RO0);
  k_trw<<<dim3(D0 / 64, H / 64, 14), 256, 0, stream>>>(conv1_w, wTT1, D0, 14 * D0);
  k_trw<<<dim3(H / 64,  H / 64, 14), 256, 0, stream>>>(conv2_w, wTT2, H, 14 * H);
  k_trw_aw<<<D0 / 64, 256, 0, stream>>>(aW1, aWT1, D0);
  k_trw_aw<<<H  / 64, 256, 0, stream>>>(aW2, aWT2, H);
  // 1. fused att1 + xa1
  k_attxa<D0><<<B, 256, 0, stream>>>(Xh, Yh, aWT1, x1ah, x2ah);
  // 2. conv1 (global_load_lds B-staging) -> lcTh/rcTh fp16
  k_conv<D0><<<560, 256, 0, stream>>>(Xh, Yh, x1ah, x2ah, wTT1, conv1_b, lcTh, rcTh);
  // 3. att2 sums
  k_att<T70, 96, H, false, true><<<B, 256, 0, stream>>>(lcTh, rcTh, nullptr, nullptr, la, ra);
  // 4. fused mean + wpool
  k_powl<<<dim3(B, 2), 256, 0, stream>>>(lcTh, rcTh, la, ra, LO1, RO1, LI1h, RI1h);
  // 5. fused att2' + xa2
  k_attxa<H><<<B, 256, 0, stream>>>(LI1h, RI1h, aWT2, x1ah, x2ah);
  // 6. conv2 -> reuse lcTh/rcTh
  k_conv<H><<<560, 256, 0, stream>>>(LI1h, RI1h, x1ah, x2ah, wTT2, conv2_b, lcTh, rcTh);
  // 7. LO2/RO2 (merged)
  k_mean2<<<dim3((B * H + 255) / 256, 2), 256, 0, stream>>>(lcTh, rcTh, LO2, RO2);
  // 8. final
  k_final<<<B, 256, 0, stream>>>(LO0, RO0, LO1, RO1, LO2, RO2, out_w, out_b, out);
}